// Round 1
// baseline (432.215 us; speedup 1.0000x reference)
//
#include <hip/hip_runtime.h>
#include <hip/hip_bf16.h>

// ---------------- workspace layout (float offsets) ----------------
// qkv:   [256][512][64]            = 8,388,608
// a1,b1: [512] each
// p2:    [4096][6] passA partials  = 24,576
// a2:    [48] (padded to 64)
// attnW/attneW: [256][16][16][64]  = 4,194,304 each
// a3,b3: [512] each
static const size_t OFF_QKV   = 0;
static const size_t OFF_A1    = 8388608;
static const size_t OFF_B1    = 8389120;
static const size_t OFF_P2    = 8389632;
static const size_t OFF_A2    = 8414208;
static const size_t OFF_ATTN  = 8414272;
static const size_t OFF_ATTNE = 12608576;
static const size_t OFF_A3    = 16802880;
static const size_t OFF_B3    = 16803392;

// ---------------- Kernel 1: qkv[n][o][i] = sum_c x[b][c][h][i] * w[o][c] ----------------
__global__ __launch_bounds__(256) void k_qkv(const float* __restrict__ x,
                                             const float* __restrict__ w,
                                             float* __restrict__ qkv)
{
    __shared__ float xs[16][68];   // [c_local][i], padded for fp4-aligned stores
    __shared__ float wsl[64][20];  // [o_local][c_local]
    const int ob = blockIdx.x;     // 0..7  (o tile of 64)
    const int n  = blockIdx.y;     // 0..255
    const int b = n >> 6, h = n & 63;
    const float* xbase = x + (size_t)b*256*4096 + (size_t)h*64; // x[b][c][h][i] = xbase[c*4096+i]
    const float* wbase = w + (size_t)ob*64*256;
    const int tid = threadIdx.x;
    const int ti = tid >> 4, tj = tid & 15;
    float acc[4][4] = {};
    for (int c0 = 0; c0 < 256; c0 += 16) {
        {
            const int r  = tid >> 4, c4 = (tid & 15) * 4;
            const float4 v = *(const float4*)(xbase + (size_t)(c0 + r)*4096 + c4);
            *(float4*)&xs[r][c4] = v;
            const int r2 = tid >> 2, cq = (tid & 3) * 4;
            const float4 wv = *(const float4*)(wbase + (size_t)r2*256 + c0 + cq);
            wsl[r2][cq+0] = wv.x; wsl[r2][cq+1] = wv.y; wsl[r2][cq+2] = wv.z; wsl[r2][cq+3] = wv.w;
        }
        __syncthreads();
        #pragma unroll
        for (int k = 0; k < 16; ++k) {
            float a_[4], b_[4];
            #pragma unroll
            for (int u = 0; u < 4; ++u) a_[u] = wsl[4*ti+u][k];
            #pragma unroll
            for (int v = 0; v < 4; ++v) b_[v] = xs[k][4*tj+v];
            #pragma unroll
            for (int u = 0; u < 4; ++u)
                #pragma unroll
                for (int v = 0; v < 4; ++v)
                    acc[u][v] = fmaf(a_[u], b_[v], acc[u][v]);
        }
        __syncthreads();
    }
    float* obase = qkv + (size_t)n*32768 + (size_t)(ob*64)*64;
    #pragma unroll
    for (int u = 0; u < 4; ++u) {
        float4 val = make_float4(acc[u][0], acc[u][1], acc[u][2], acc[u][3]);
        *(float4*)(obase + (size_t)(4*ti+u)*64 + 4*tj) = val;
    }
}

// ---------------- Kernel 2: bn1 stats -> folded affine a1,b1 ----------------
__global__ __launch_bounds__(256) void k_bn1(const float* __restrict__ qkv,
                                             const float* __restrict__ gamma,
                                             const float* __restrict__ beta,
                                             float* __restrict__ a1, float* __restrict__ b1)
{
    const int o = blockIdx.x;          // 0..511
    const int tid = threadIdx.x;
    float s = 0.f, s2 = 0.f;
    const float* base = qkv + (size_t)o*64;
    for (int t = tid; t < 16384; t += 256) {
        const int n = t >> 6, i = t & 63;
        const float v = base[(size_t)n*32768 + i];
        s += v; s2 += v*v;
    }
    __shared__ float rs[4], rs2[4];
    #pragma unroll
    for (int off = 32; off; off >>= 1) { s += __shfl_down(s, off); s2 += __shfl_down(s2, off); }
    if ((tid & 63) == 0) { rs[tid>>6] = s; rs2[tid>>6] = s2; }
    __syncthreads();
    if (tid == 0) {
        const float S  = rs[0]+rs[1]+rs[2]+rs[3];
        const float S2 = rs2[0]+rs2[1]+rs2[2]+rs2[3];
        const float mean = S * (1.f/16384.f);
        const float var  = S2 * (1.f/16384.f) - mean*mean;
        const float A = gamma[o] * rsqrtf(var + 1e-5f);
        a1[o] = A;
        b1[o] = beta[o] - mean*A;
    }
}

// ---------------- Kernels 3/5: per-(n,g) core.  PASSB=0: bn2 stat partials.
//                  PASSB=1: z = a*qk+b*qe+c*ke, softmax, attn/attn_e.  ----------------
template<int PASSB>
__global__ __launch_bounds__(256) void k_pass(const float* __restrict__ qkv,
    const float* __restrict__ a1, const float* __restrict__ b1,
    const float* __restrict__ rel_emb,
    float* __restrict__ p2,
    const float* __restrict__ a2,
    float* __restrict__ attnW, float* __restrict__ attneW)
{
    __shared__ float remb[PASSB ? 32 : 16][128];
    __shared__ float qkb[16][64];
    __shared__ float vb[PASSB ? 16 : 1][64];
    __shared__ float qe[64][65];
    __shared__ float ke[64][65];
    __shared__ float red[4][6];

    const int bx = blockIdx.x;
    const int n = bx >> 4, g = bx & 15;
    const int tid = threadIdx.x;

    const int NR = PASSB ? 32 : 16;
    for (int t = tid; t < NR*127; t += 256) {
        const int r = t / 127, col = t - r*127;
        remb[r][col] = rel_emb[r*127 + col];
    }
    const float* qbase = qkv + (size_t)n*32768 + (size_t)(g*32)*64;
    for (int t = tid; t < 1024; t += 256) {
        const int c = t >> 6, i = t & 63;
        const int o = g*32 + c;
        qkb[c][i] = fmaf(a1[o], qbase[(size_t)c*64 + i], b1[o]);
        if (PASSB) {
            const int o2 = o + 16;
            vb[c][i] = fmaf(a1[o2], qbase[(size_t)(c+16)*64 + i], b1[o2]);
        }
    }
    __syncthreads();

    // qe[i][j] = sum_{c<8} q[c][i]*remb[c][i-j+63] ; ke with rows 8..15
    float sqe=0.f, s2qe=0.f, ske=0.f, s2ke=0.f;
    for (int t = tid; t < 4096; t += 256) {
        const int i = t >> 6, j = t & 63;
        const int d = i - j + 63;
        float aq = 0.f, ak = 0.f;
        #pragma unroll
        for (int c = 0; c < 8; ++c) {
            aq = fmaf(qkb[c][i],   remb[c][d],   aq);
            ak = fmaf(qkb[c+8][i], remb[c+8][d], ak);
        }
        qe[i][j] = aq; ke[i][j] = ak;
        if (!PASSB) { sqe += aq; s2qe += aq*aq; ske += ak; s2ke += ak*ak; }
    }
    __syncthreads();

    // qk[i][j] = sum_k qe[k][i] * ke[k][j]  (4x4 register tile per thread)
    const int ti = tid >> 4, tj = tid & 15;
    float acc[4][4] = {};
    for (int k = 0; k < 64; ++k) {
        float a_[4], b_[4];
        #pragma unroll
        for (int u = 0; u < 4; ++u) a_[u] = qe[k][4*ti+u];
        #pragma unroll
        for (int v = 0; v < 4; ++v) b_[v] = ke[k][4*tj+v];
        #pragma unroll
        for (int u = 0; u < 4; ++u)
            #pragma unroll
            for (int v = 0; v < 4; ++v)
                acc[u][v] = fmaf(a_[u], b_[v], acc[u][v]);
    }

    if (!PASSB) {
        float sqk = 0.f, s2qk = 0.f;
        #pragma unroll
        for (int u = 0; u < 4; ++u)
            #pragma unroll
            for (int v = 0; v < 4; ++v) { const float q_ = acc[u][v]; sqk += q_; s2qk += q_*q_; }
        float vals[6] = {sqk, s2qk, sqe, s2qe, ske, s2ke};
        #pragma unroll
        for (int q = 0; q < 6; ++q) {
            float v = vals[q];
            #pragma unroll
            for (int off = 32; off; off >>= 1) v += __shfl_down(v, off);
            if ((tid & 63) == 0) red[tid>>6][q] = v;
        }
        __syncthreads();
        if (tid < 6) p2[(size_t)bx*6 + tid] = red[0][tid]+red[1][tid]+red[2][tid]+red[3][tid];
        return;
    }

    // ---------------- pass B only ----------------
    __syncthreads();  // all qk reads of qe/ke done before overwrite
    const float c_qk = a2[g], c_qe = a2[16+g], c_ke = a2[32+g];
    #pragma unroll
    for (int u = 0; u < 4; ++u)
        #pragma unroll
        for (int v = 0; v < 4; ++v) {
            const int i = 4*ti+u, j = 4*tj+v;
            qe[i][j] = c_qk*acc[u][v] + c_qe*qe[i][j] + c_ke*ke[i][j];
        }
    __syncthreads();

    // softmax over j, one wave handles 16 rows
    const int wv = tid >> 6, lane = tid & 63;
    for (int rr = 0; rr < 16; ++rr) {
        const int i = wv*16 + rr;
        float zv = qe[i][lane];
        float m = zv;
        #pragma unroll
        for (int off = 32; off; off >>= 1) m = fmaxf(m, __shfl_xor(m, off));
        const float e = __expf(zv - m);
        float s = e;
        #pragma unroll
        for (int off = 32; off; off >>= 1) s += __shfl_xor(s, off);
        qe[i][lane] = e / s;
    }
    __syncthreads();

    // attn[c][i] = sum_j p[i][j]*v[c][j] ; attn_e[c][i] = sum_j p[i][j]*remb[16+c][i-j+63]
    float* aw = attnW  + ((size_t)n*16 + g)*1024;
    float* ew = attneW + ((size_t)n*16 + g)*1024;
    for (int t = tid; t < 1024; t += 256) {
        const int c = t >> 6, i = t & 63;
        float sa = 0.f, se = 0.f;
        #pragma unroll 8
        for (int j = 0; j < 64; ++j) {
            const float pv = qe[i][j];
            sa = fmaf(pv, vb[c][j], sa);
            se = fmaf(pv, remb[16+c][i - j + 63], se);
        }
        aw[(size_t)c*64 + i] = sa;
        ew[(size_t)c*64 + i] = se;
    }
}

// ---------------- Kernel 4: bn2 finalize (scales only; constants cancel in softmax) ----------------
__global__ void k_bn2(const float* __restrict__ p2, const float* __restrict__ gamma2,
                      float* __restrict__ a2)
{
    const int tid = threadIdx.x;   // 64 threads, 1 wave
    for (int ch = 0; ch < 48; ++ch) {
        const int kind = ch >> 4, g = ch & 15;
        float s = 0.f, s2 = 0.f;
        for (int nn = tid; nn < 256; nn += 64) {
            const float* p = p2 + ((size_t)nn*16 + g)*6 + 2*kind;
            s += p[0]; s2 += p[1];
        }
        #pragma unroll
        for (int off = 32; off; off >>= 1) { s += __shfl_down(s, off); s2 += __shfl_down(s2, off); }
        if (tid == 0) {
            const float mean = s * (1.f/1048576.f);
            const float var  = s2 * (1.f/1048576.f) - mean*mean;
            a2[ch] = gamma2[ch] * rsqrtf(var + 1e-5f);
        }
    }
}

// ---------------- Kernel 6: bn3 stats -> a3,b3 ----------------
__global__ __launch_bounds__(256) void k_bn3(const float* __restrict__ attnW,
                                             const float* __restrict__ attneW,
                                             const float* __restrict__ gamma,
                                             const float* __restrict__ beta,
                                             float* __restrict__ a3, float* __restrict__ b3)
{
    const int o = blockIdx.x;          // 0..511 ; o = g*32 + 2c + s
    const int g = o >> 5, rem = o & 31, c = rem >> 1, sflag = rem & 1;
    const float* src = (sflag ? attneW : attnW) + (size_t)g*1024 + (size_t)c*64;
    const int tid = threadIdx.x;
    float s = 0.f, s2 = 0.f;
    for (int t = tid; t < 16384; t += 256) {
        const int n = t >> 6, i = t & 63;
        const float v = src[(size_t)n*16384 + i];
        s += v; s2 += v*v;
    }
    __shared__ float rs[4], rs2[4];
    #pragma unroll
    for (int off = 32; off; off >>= 1) { s += __shfl_down(s, off); s2 += __shfl_down(s2, off); }
    if ((tid & 63) == 0) { rs[tid>>6] = s; rs2[tid>>6] = s2; }
    __syncthreads();
    if (tid == 0) {
        const float S  = rs[0]+rs[1]+rs[2]+rs[3];
        const float S2 = rs2[0]+rs2[1]+rs2[2]+rs2[3];
        const float mean = S * (1.f/16384.f);
        const float var  = S2 * (1.f/16384.f) - mean*mean;
        const float A = gamma[o] * rsqrtf(var + 1e-5f);
        a3[o] = A;
        b3[o] = beta[o] - mean*A;
    }
}

// ---------------- Kernel 7: apply bn3, sum channel pairs, transpose to (B,256,H,W) ----------------
__global__ __launch_bounds__(256) void k_out(const float* __restrict__ attnW,
                                             const float* __restrict__ attneW,
                                             const float* __restrict__ a3,
                                             const float* __restrict__ b3,
                                             float* __restrict__ out)
{
    const int idx = blockIdx.x*256 + threadIdx.x;   // 4,194,304 total
    const int i  = idx & 63;
    const int h  = (idx >> 6) & 63;
    const int oc = (idx >> 12) & 255;
    const int b  = idx >> 20;
    const int g = oc >> 4, c = oc & 15;
    const int n = b*64 + h;
    const size_t src = ((size_t)n*16 + g)*1024 + (size_t)c*64 + i;
    const int o0 = g*32 + 2*c;
    out[idx] = a3[o0]*attnW[src] + a3[o0+1]*attneW[src] + (b3[o0] + b3[o0+1]);
}

extern "C" void kernel_launch(void* const* d_in, const int* in_sizes, int n_in,
                              void* d_out, int out_size, void* d_ws, size_t ws_size,
                              hipStream_t stream) {
    const float* x    = (const float*)d_in[0];
    const float* w    = (const float*)d_in[1];
    const float* g1   = (const float*)d_in[2];
    const float* be1  = (const float*)d_in[3];
    const float* remb = (const float*)d_in[4];
    const float* g2   = (const float*)d_in[5];
    // d_in[6] = bn2_beta: additive constant cancels in softmax -> unused
    const float* g3   = (const float*)d_in[7];
    const float* be3  = (const float*)d_in[8];
    float* out = (float*)d_out;
    float* ws  = (float*)d_ws;

    float* qkv   = ws + OFF_QKV;
    float* a1    = ws + OFF_A1;
    float* b1    = ws + OFF_B1;
    float* p2    = ws + OFF_P2;
    float* a2    = ws + OFF_A2;
    float* attnW = ws + OFF_ATTN;
    float* attneW= ws + OFF_ATTNE;
    float* a3    = ws + OFF_A3;
    float* b3    = ws + OFF_B3;

    k_qkv<<<dim3(8, 256), 256, 0, stream>>>(x, w, qkv);
    k_bn1<<<512, 256, 0, stream>>>(qkv, g1, be1, a1, b1);
    k_pass<0><<<4096, 256, 0, stream>>>(qkv, a1, b1, remb, p2, nullptr, nullptr, nullptr);
    k_bn2<<<1, 64, 0, stream>>>(p2, g2, a2);
    k_pass<1><<<4096, 256, 0, stream>>>(qkv, a1, b1, remb, nullptr, a2, attnW, attneW);
    k_bn3<<<512, 256, 0, stream>>>(attnW, attneW, g3, be3, a3, b3);
    k_out<<<16384, 256, 0, stream>>>(attnW, attneW, a3, b3, out);
}

// Round 3
// 219.883 us; speedup vs baseline: 1.9657x; 1.9657x over previous
//
#include <hip/hip_runtime.h>
#include <hip/hip_bf16.h>

typedef short s16x8 __attribute__((ext_vector_type(8)));
typedef float f32x4 __attribute__((ext_vector_type(4)));

static __device__ __forceinline__ unsigned short f2bf(float f){
    unsigned int u = __float_as_uint(f);
    u += 0x7fffu + ((u >> 16) & 1u);
    return (unsigned short)(u >> 16);
}
static __device__ __forceinline__ float bf2f(unsigned short h){
    return __uint_as_float(((unsigned int)h) << 16);
}

// ---------------- workspace layout (float offsets) ----------------
static const size_t OFF_QKV   = 0;
static const size_t OFF_A1    = 8388608;
static const size_t OFF_B1    = 8389120;
static const size_t OFF_P2    = 8389632;
static const size_t OFF_A2    = 8414208;
static const size_t OFF_ATTN  = 8414272;
static const size_t OFF_ATTNE = 12608576;
static const size_t OFF_A3    = 16802880;
static const size_t OFF_B3    = 16803392;

// ---------------- Kernel 1: qkv[n][o][i] = sum_c x[b][c][h][i] * w[o][c] ----------------
__global__ __launch_bounds__(256) void k_qkv(const float* __restrict__ x,
                                             const float* __restrict__ w,
                                             float* __restrict__ qkv)
{
    __shared__ float xs[16][68];
    __shared__ float wsl[64][20];
    const int ob = blockIdx.x;     // 0..7
    const int n  = blockIdx.y;     // 0..255
    const int b = n >> 6, h = n & 63;
    const float* xbase = x + (size_t)b*256*4096 + (size_t)h*64;
    const float* wbase = w + (size_t)ob*64*256;
    const int tid = threadIdx.x;
    const int ti = tid >> 4, tj = tid & 15;
    float acc[4][4] = {};
    for (int c0 = 0; c0 < 256; c0 += 16) {
        {
            const int r  = tid >> 4, c4 = (tid & 15) * 4;
            const float4 v = *(const float4*)(xbase + (size_t)(c0 + r)*4096 + c4);
            *(float4*)&xs[r][c4] = v;
            const int r2 = tid >> 2, cq = (tid & 3) * 4;
            const float4 wv = *(const float4*)(wbase + (size_t)r2*256 + c0 + cq);
            wsl[r2][cq+0] = wv.x; wsl[r2][cq+1] = wv.y; wsl[r2][cq+2] = wv.z; wsl[r2][cq+3] = wv.w;
        }
        __syncthreads();
        #pragma unroll
        for (int k = 0; k < 16; ++k) {
            float a_[4], b_[4];
            #pragma unroll
            for (int u = 0; u < 4; ++u) a_[u] = wsl[4*ti+u][k];
            #pragma unroll
            for (int v = 0; v < 4; ++v) b_[v] = xs[k][4*tj+v];
            #pragma unroll
            for (int u = 0; u < 4; ++u)
                #pragma unroll
                for (int v = 0; v < 4; ++v)
                    acc[u][v] = fmaf(a_[u], b_[v], acc[u][v]);
        }
        __syncthreads();
    }
    float* obase = qkv + (size_t)n*32768 + (size_t)(ob*64)*64;
    #pragma unroll
    for (int u = 0; u < 4; ++u) {
        float4 val = make_float4(acc[u][0], acc[u][1], acc[u][2], acc[u][3]);
        *(float4*)(obase + (size_t)(4*ti+u)*64 + 4*tj) = val;
    }
}

// ---------------- Kernel 2: bn1 stats -> folded affine a1,b1 ----------------
__global__ __launch_bounds__(256) void k_bn1(const float* __restrict__ qkv,
                                             const float* __restrict__ gamma,
                                             const float* __restrict__ beta,
                                             float* __restrict__ a1, float* __restrict__ b1)
{
    const int o = blockIdx.x;
    const int tid = threadIdx.x;
    float s = 0.f, s2 = 0.f;
    const float* base = qkv + (size_t)o*64;
    for (int t = tid; t < 16384; t += 256) {
        const int n = t >> 6, i = t & 63;
        const float v = base[(size_t)n*32768 + i];
        s += v; s2 += v*v;
    }
    __shared__ float rs[4], rs2[4];
    #pragma unroll
    for (int off = 32; off; off >>= 1) { s += __shfl_down(s, off); s2 += __shfl_down(s2, off); }
    if ((tid & 63) == 0) { rs[tid>>6] = s; rs2[tid>>6] = s2; }
    __syncthreads();
    if (tid == 0) {
        const float S  = rs[0]+rs[1]+rs[2]+rs[3];
        const float S2 = rs2[0]+rs2[1]+rs2[2]+rs2[3];
        const float mean = S * (1.f/16384.f);
        const float var  = S2 * (1.f/16384.f) - mean*mean;
        const float A = gamma[o] * rsqrtf(var + 1e-5f);
        a1[o] = A;
        b1[o] = beta[o] - mean*A;
    }
}

// ---------------- Kernels 3/5: per-(n,g) MFMA core ----------------
// Shared-memory regions (bytes, dynamic; SHM = 39040):
//   A: 0..20480     qkT[64][32](4096) + rembTq[128][32](8192) + rembTk[128][32](8192)
//                   passB overlays with PSt[64][136] (17408)
//   D: 20480..29696 qeT[64][72] -> later pT[64][72]
//   E: 29696..38912 keT[64][72] -> later rembV[16][136](4352)@29696 + vbL[16][72](2304)@34048
//   red: 38912..39008 (passA only)
template<int PASSB>
__global__ __launch_bounds__(256) void k_pass2(const float* __restrict__ qkv,
    const float* __restrict__ a1, const float* __restrict__ b1,
    const float* __restrict__ rel_emb,
    float* __restrict__ p2, const float* __restrict__ a2,
    float* __restrict__ attnW, float* __restrict__ attneW)
{
    extern __shared__ char sm[];
    unsigned short (* const qkT)[32]    = (unsigned short(*)[32])(sm);
    unsigned short (* const rembTq)[32] = (unsigned short(*)[32])(sm + 4096);
    unsigned short (* const rembTk)[32] = (unsigned short(*)[32])(sm + 12288);
    unsigned short (* const PSt)[136]   = (unsigned short(*)[136])(sm);
    unsigned short (* const qeT)[72]    = (unsigned short(*)[72])(sm + 20480);
    unsigned short (* const pT)[72]     = (unsigned short(*)[72])(sm + 20480);
    unsigned short (* const keT)[72]    = (unsigned short(*)[72])(sm + 29696);
    unsigned short (* const rembV)[136] = (unsigned short(*)[136])(sm + 29696);
    unsigned short (* const vbL)[72]    = (unsigned short(*)[72])(sm + 34048);
    float* const red = (float*)(sm + 38912);

    const int bx = blockIdx.x, n = bx >> 4, g = bx & 15;
    const int tid = threadIdx.x;
    const int w = tid >> 6, l = tid & 63, lb = l & 15, h = l >> 4;

    // ---- stage 0: zero rembTq/rembTk (16384 B)
    {
        int4 z4; z4.x = z4.y = z4.z = z4.w = 0;
        int4* dst = (int4*)(sm + 4096);
        for (int t = tid; t < 1024; t += 256) dst[t] = z4;
    }
    __syncthreads();

    // ---- stage 1: staging
    {   // qkT: cols 0..7 = q channels, 8..15 = k channels, 16..31 = 0
        const int a = tid & 63, c0 = (tid >> 6) * 4;
        unsigned long long pk = 0;
        #pragma unroll
        for (int u = 0; u < 4; ++u) {
            const int o = g*32 + c0 + u;
            const float val = a1[o] * qkv[(size_t)n*32768 + (size_t)o*64 + a] + b1[o];
            pk |= (unsigned long long)f2bf(val) << (16*u);
        }
        *(unsigned long long*)&qkT[a][c0] = pk;
        *(unsigned long long*)&qkT[a][16 + c0] = 0ull;
    }
    {   // rembTq[d][0..7] = rel_emb[c][d]; rembTk[d][8..15] = rel_emb[8+c][d]
        const int d = tid >> 1, half = tid & 1;
        if (d < 127) {
            if (half == 0) {
                unsigned long long p0 = 0, p1 = 0;
                #pragma unroll
                for (int c = 0; c < 4; ++c) p0 |= (unsigned long long)f2bf(rel_emb[c*127 + d]) << (16*c);
                #pragma unroll
                for (int c = 0; c < 4; ++c) p1 |= (unsigned long long)f2bf(rel_emb[(4+c)*127 + d]) << (16*c);
                *(unsigned long long*)&rembTq[d][0] = p0;
                *(unsigned long long*)&rembTq[d][4] = p1;
            } else {
                unsigned long long p0 = 0, p1 = 0;
                #pragma unroll
                for (int c = 0; c < 4; ++c) p0 |= (unsigned long long)f2bf(rel_emb[(8+c)*127 + d]) << (16*c);
                #pragma unroll
                for (int c = 0; c < 4; ++c) p1 |= (unsigned long long)f2bf(rel_emb[(12+c)*127 + d]) << (16*c);
                *(unsigned long long*)&rembTk[d][8] = p0;
                *(unsigned long long*)&rembTk[d][12] = p1;
            }
        }
    }
    float vreg[4] = {0,0,0,0};
    float evreg[8] = {0,0,0,0,0,0,0,0};
    if (PASSB) {   // bn1-normalized v + remb_v into registers (LDS still holds keT)
        const int cv = tid >> 4, ap = (tid & 15) * 4;
        const int o = g*32 + 16 + cv;
        const float A = a1[o], Bc = b1[o];
        const float4 vv = *(const float4*)&qkv[(size_t)n*32768 + (size_t)o*64 + ap];
        vreg[0] = A*vv.x + Bc; vreg[1] = A*vv.y + Bc;
        vreg[2] = A*vv.z + Bc; vreg[3] = A*vv.w + Bc;
        const int d0 = (tid & 15) * 8;
        #pragma unroll
        for (int kk = 0; kk < 8; ++kk)
            evreg[kk] = (d0 + kk < 127) ? rel_emb[(16+cv)*127 + d0 + kk] : 0.f;
    }
    __syncthreads();

    // ---- stage 2: qeS/keS GEMMs (64x128, K=32) + skew scatter into qeT/keT
    // qeS[a][d] = sum_c q[c][a]*remb_q[c][d]; qe[i][j] = qeS[i][i-j+63]
    // qk A-storage: qeT[i][k] = qe[k][i]  => scatter qeS[a][d] -> qeT[a+63-d][a]
    float sqe=0.f, s2qe=0.f, ske=0.f, s2ke=0.f;
    {
        const int a0 = w*16;
        const s16x8 afr = *(const s16x8*)&qkT[a0 + lb][h*8];
        #pragma unroll
        for (int dt = 0; dt < 8; ++dt) {
            const s16x8 bq = *(const s16x8*)&rembTq[dt*16 + lb][h*8];
            const s16x8 bk = *(const s16x8*)&rembTk[dt*16 + lb][h*8];
            f32x4 zz = {0.f,0.f,0.f,0.f};
            f32x4 cq = __builtin_amdgcn_mfma_f32_16x16x32_bf16(afr, bq, zz, 0,0,0);
            f32x4 ck = __builtin_amdgcn_mfma_f32_16x16x32_bf16(afr, bk, zz, 0,0,0);
            const int d = dt*16 + lb;
            #pragma unroll
            for (int r = 0; r < 4; ++r) {
                const int a = a0 + h*4 + r;
                const int i = a + 63 - d;
                if (i >= 0 && i < 64) {
                    const float vq = cq[r], vk = ck[r];
                    qeT[i][a] = f2bf(vq);
                    keT[i][a] = f2bf(vk);
                    if (!PASSB) { sqe += vq; s2qe += vq*vq; ske += vk; s2ke += vk*vk; }
                }
            }
        }
    }
    __syncthreads();

    // ---- stage 3: qk GEMM (64x64, K=64). A=qeT, B-storage=keT.
    const int i0 = w*16;
    f32x4 acc[4];
    #pragma unroll
    for (int jt = 0; jt < 4; ++jt) { acc[jt][0]=0.f; acc[jt][1]=0.f; acc[jt][2]=0.f; acc[jt][3]=0.f; }
    #pragma unroll
    for (int kc = 0; kc < 2; ++kc) {
        const s16x8 aq = *(const s16x8*)&qeT[i0 + lb][kc*32 + h*8];
        #pragma unroll
        for (int jt = 0; jt < 4; ++jt) {
            const s16x8 bk2 = *(const s16x8*)&keT[jt*16 + lb][kc*32 + h*8];
            acc[jt] = __builtin_amdgcn_mfma_f32_16x16x32_bf16(aq, bk2, acc[jt], 0,0,0);
        }
    }

    if (!PASSB) {
        float sqk=0.f, s2qk=0.f;
        #pragma unroll
        for (int jt = 0; jt < 4; ++jt)
            #pragma unroll
            for (int r = 0; r < 4; ++r) { const float q_ = acc[jt][r]; sqk += q_; s2qk += q_*q_; }
        float vals[6] = {sqk, s2qk, sqe, s2qe, ske, s2ke};
        #pragma unroll
        for (int q = 0; q < 6; ++q) {
            float v = vals[q];
            #pragma unroll
            for (int off = 32; off; off >>= 1) v += __shfl_xor(v, off);
            if (l == 0) red[w*6 + q] = v;
        }
        __syncthreads();
        if (tid < 6) p2[(size_t)bx*6 + tid] = red[tid] + red[6+tid] + red[12+tid] + red[18+tid];
        return;
    }

    // ---- passB: zero PSt (region A is dead now; barrier below orders vs p-writes)
    {
        int4 z4; z4.x=z4.y=z4.z=z4.w=0;
        int4* dst = (int4*)sm;
        for (int t = tid; t < 1088; t += 256) dst[t] = z4;
    }

    // ---- stage 4: z-combine + in-register softmax
    const float c_qk = a2[g], c_qe = a2[16+g], c_ke = a2[32+g];
    float p[4][4];
    #pragma unroll
    for (int jt = 0; jt < 4; ++jt) {
        const unsigned long long q4 = *(const unsigned long long*)&qeT[jt*16 + lb][i0 + 4*h];
        const unsigned long long k4 = *(const unsigned long long*)&keT[jt*16 + lb][i0 + 4*h];
        #pragma unroll
        for (int r = 0; r < 4; ++r) {
            p[jt][r] = c_qk*acc[jt][r]
                     + c_qe*bf2f((unsigned short)(q4 >> (16*r)))
                     + c_ke*bf2f((unsigned short)(k4 >> (16*r)));
        }
    }
    #pragma unroll
    for (int r = 0; r < 4; ++r) {
        float m = fmaxf(fmaxf(p[0][r], p[1][r]), fmaxf(p[2][r], p[3][r]));
        #pragma unroll
        for (int mk = 8; mk; mk >>= 1) m = fmaxf(m, __shfl_xor(m, mk));
        float s = 0.f;
        #pragma unroll
        for (int jt = 0; jt < 4; ++jt) { p[jt][r] = __expf(p[jt][r] - m); s += p[jt][r]; }
        #pragma unroll
        for (int mk = 8; mk; mk >>= 1) s += __shfl_xor(s, mk);
        const float inv = 1.f / s;
        #pragma unroll
        for (int jt = 0; jt < 4; ++jt) p[jt][r] *= inv;
    }
    __syncthreads();   // qeT/keT reads + PSt zeroing complete before overwrite

    // ---- stage 5: scatter p -> pT and PSt (skewed); stage vbL/rembV from registers
    #pragma unroll
    for (int jt = 0; jt < 4; ++jt)
        #pragma unroll
        for (int r = 0; r < 4; ++r) {
            const int i = i0 + 4*h + r, j = jt*16 + lb;
            const unsigned short pb = f2bf(p[jt][r]);
            pT[i][j] = pb;
            PSt[i][i + 63 - j] = pb;
        }
    {
        const int cv = tid >> 4, ap = (tid & 15)*4;
        unsigned long long pk = 0;
        #pragma unroll
        for (int u = 0; u < 4; ++u) pk |= (unsigned long long)f2bf(vreg[u]) << (16*u);
        *(unsigned long long*)&vbL[cv][ap] = pk;
        const int d0 = (tid & 15)*8;
        unsigned long long e0 = 0, e1 = 0;
        #pragma unroll
        for (int u = 0; u < 4; ++u) e0 |= (unsigned long long)f2bf(evreg[u]) << (16*u);
        #pragma unroll
        for (int u = 0; u < 4; ++u) e1 |= (unsigned long long)f2bf(evreg[4+u]) << (16*u);
        *(unsigned long long*)&rembV[cv][d0]   = e0;
        *(unsigned long long*)&rembV[cv][d0+4] = e1;
    }
    __syncthreads();

    // ---- stage 6: attn = v.pT (16x64, K=64), attn_e = remb_v.PSt^T (16x64, K=128)
    f32x4 accA = {0.f,0.f,0.f,0.f}, accE = {0.f,0.f,0.f,0.f};
    #pragma unroll
    for (int kc = 0; kc < 2; ++kc) {
        const s16x8 av = *(const s16x8*)&vbL[lb][kc*32 + h*8];
        const s16x8 bp = *(const s16x8*)&pT[i0 + lb][kc*32 + h*8];
        accA = __builtin_amdgcn_mfma_f32_16x16x32_bf16(av, bp, accA, 0,0,0);
    }
    #pragma unroll
    for (int kc = 0; kc < 4; ++kc) {
        const s16x8 ae = *(const s16x8*)&rembV[lb][kc*32 + h*8];
        const s16x8 bs = *(const s16x8*)&PSt[i0 + lb][kc*32 + h*8];
        accE = __builtin_amdgcn_mfma_f32_16x16x32_bf16(ae, bs, accE, 0,0,0);
    }
    float* aw = attnW  + ((size_t)n*16 + g)*1024;
    float* ew = attneW + ((size_t)n*16 + g)*1024;
    #pragma unroll
    for (int r = 0; r < 4; ++r) {
        aw[(4*h + r)*64 + i0 + lb] = accA[r];
        ew[(4*h + r)*64 + i0 + lb] = accE[r];
    }
}

// ---------------- Kernel 4: bn2 finalize (scales only) ----------------
__global__ void k_bn2(const float* __restrict__ p2, const float* __restrict__ gamma2,
                      float* __restrict__ a2)
{
    const int tid = threadIdx.x;   // 64 threads
    for (int ch = 0; ch < 48; ++ch) {
        const int kind = ch >> 4, g = ch & 15;
        float s = 0.f, s2 = 0.f;
        for (int nn = tid; nn < 256; nn += 64) {
            const float* p = p2 + ((size_t)nn*16 + g)*6 + 2*kind;
            s += p[0]; s2 += p[1];
        }
        #pragma unroll
        for (int off = 32; off; off >>= 1) { s += __shfl_down(s, off); s2 += __shfl_down(s2, off); }
        if (tid == 0) {
            const float mean = s * (1.f/1048576.f);
            const float var  = s2 * (1.f/1048576.f) - mean*mean;
            a2[ch] = gamma2[ch] * rsqrtf(var + 1e-5f);
        }
    }
}

// ---------------- Kernel 6: bn3 stats -> a3,b3 ----------------
__global__ __launch_bounds__(256) void k_bn3(const float* __restrict__ attnW,
                                             const float* __restrict__ attneW,
                                             const float* __restrict__ gamma,
                                             const float* __restrict__ beta,
                                             float* __restrict__ a3, float* __restrict__ b3)
{
    const int o = blockIdx.x;
    const int g = o >> 5, rem = o & 31, c = rem >> 1, sflag = rem & 1;
    const float* src = (sflag ? attneW : attnW) + (size_t)g*1024 + (size_t)c*64;
    const int tid = threadIdx.x;
    float s = 0.f, s2 = 0.f;
    for (int t = tid; t < 16384; t += 256) {
        const int n = t >> 6, i = t & 63;
        const float v = src[(size_t)n*16384 + i];
        s += v; s2 += v*v;
    }
    __shared__ float rs[4], rs2[4];
    #pragma unroll
    for (int off = 32; off; off >>= 1) { s += __shfl_down(s, off); s2 += __shfl_down(s2, off); }
    if ((tid & 63) == 0) { rs[tid>>6] = s; rs2[tid>>6] = s2; }
    __syncthreads();
    if (tid == 0) {
        const float S  = rs[0]+rs[1]+rs[2]+rs[3];
        const float S2 = rs2[0]+rs2[1]+rs2[2]+rs2[3];
        const float mean = S * (1.f/16384.f);
        const float var  = S2 * (1.f/16384.f) - mean*mean;
        const float A = gamma[o] * rsqrtf(var + 1e-5f);
        a3[o] = A;
        b3[o] = beta[o] - mean*A;
    }
}

// ---------------- Kernel 7: apply bn3, sum channel pairs, transpose ----------------
__global__ __launch_bounds__(256) void k_out(const float* __restrict__ attnW,
                                             const float* __restrict__ attneW,
                                             const float* __restrict__ a3,
                                             const float* __restrict__ b3,
                                             float* __restrict__ out)
{
    const int idx = blockIdx.x*256 + threadIdx.x;
    const int i  = idx & 63;
    const int h  = (idx >> 6) & 63;
    const int oc = (idx >> 12) & 255;
    const int b  = idx >> 20;
    const int g = oc >> 4, c = oc & 15;
    const int n = b*64 + h;
    const size_t src = ((size_t)n*16 + g)*1024 + (size_t)c*64 + i;
    const int o0 = g*32 + 2*c;
    out[idx] = a3[o0]*attnW[src] + a3[o0+1]*attneW[src] + (b3[o0] + b3[o0+1]);
}

extern "C" void kernel_launch(void* const* d_in, const int* in_sizes, int n_in,
                              void* d_out, int out_size, void* d_ws, size_t ws_size,
                              hipStream_t stream) {
    const float* x    = (const float*)d_in[0];
    const float* w    = (const float*)d_in[1];
    const float* g1   = (const float*)d_in[2];
    const float* be1  = (const float*)d_in[3];
    const float* remb = (const float*)d_in[4];
    const float* g2   = (const float*)d_in[5];
    const float* g3   = (const float*)d_in[7];
    const float* be3  = (const float*)d_in[8];
    float* out = (float*)d_out;
    float* ws  = (float*)d_ws;

    float* qkv   = ws + OFF_QKV;
    float* a1    = ws + OFF_A1;
    float* b1    = ws + OFF_B1;
    float* p2    = ws + OFF_P2;
    float* a2    = ws + OFF_A2;
    float* attnW = ws + OFF_ATTN;
    float* attneW= ws + OFF_ATTNE;
    float* a3    = ws + OFF_A3;
    float* b3    = ws + OFF_B3;

    const int SHM = 39040;
    k_qkv<<<dim3(8, 256), 256, 0, stream>>>(x, w, qkv);
    k_bn1<<<512, 256, 0, stream>>>(qkv, g1, be1, a1, b1);
    k_pass2<0><<<4096, 256, SHM, stream>>>(qkv, a1, b1, remb, p2, nullptr, nullptr, nullptr);
    k_bn2<<<1, 64, 0, stream>>>(p2, g2, a2);
    k_pass2<1><<<4096, 256, SHM, stream>>>(qkv, a1, b1, remb, nullptr, a2, attnW, attneW);
    k_bn3<<<512, 256, 0, stream>>>(attnW, attneW, g3, be3, a3, b3);
    k_out<<<16384, 256, 0, stream>>>(attnW, attneW, a3, b3, out);
}

// Round 6
// 200.665 us; speedup vs baseline: 2.1539x; 1.0958x over previous
//
#include <hip/hip_runtime.h>
#include <hip/hip_bf16.h>

typedef short s16x8 __attribute__((ext_vector_type(8)));
typedef float f32x4 __attribute__((ext_vector_type(4)));

static __device__ __forceinline__ unsigned short f2bf(float f){
    unsigned int u = __float_as_uint(f);
    u += 0x7fffu + ((u >> 16) & 1u);
    return (unsigned short)(u >> 16);
}
static __device__ __forceinline__ float bf2f(unsigned short h){
    return __uint_as_float(((unsigned int)h) << 16);
}

// ---------------- workspace layout (float offsets) ----------------
static const size_t OFF_QKV   = 0;
static const size_t OFF_A1    = 8388608;
static const size_t OFF_B1    = 8389120;
static const size_t OFF_P2    = 8389632;
static const size_t OFF_A2    = 8414208;
static const size_t OFF_ATTN  = 8414272;
static const size_t OFF_ATTNE = 12608576;
static const size_t OFF_A3    = 16802880;
static const size_t OFF_B3    = 16803392;
// transient (pre-passB) overlays inside the attnW/attneW span:
static const size_t OFF_XTH = OFF_ATTN;               // bf16[16384][256] = 2,097,152 floats
static const size_t OFF_XTL = OFF_ATTN + 2097152;     // bf16[16384][256] = 2,097,152 floats
static const size_t OFF_WH  = OFF_ATTN + 4194304;     // bf16[512][256]  = 65,536 floats
static const size_t OFF_WL  = OFF_ATTN + 4259840;     // bf16[512][256]  = 65,536 floats (FIX: was +32768, overlapped wh)

// ---------------- Kernel 0a: split+transpose x -> xT_hi/xT_lo [(n,i)][c] bf16 ----------------
__global__ __launch_bounds__(256) void k_split(const float* __restrict__ x,
                                               unsigned short* __restrict__ xTh,
                                               unsigned short* __restrict__ xTl)
{
    __shared__ unsigned short xs[64*264];   // 33,792 B
    const int n = blockIdx.x;               // 0..255 = (b,h)
    const int b = n >> 6, h = n & 63;
    const float* xbase = x + (size_t)b*256*4096 + (size_t)h*64;  // [c*4096 + i]
    const int tid = threadIdx.x;
    const int iw = tid >> 2, cch = (tid & 3) * 64;
    const size_t row = (size_t)n*64 + iw;

    // phase H
    {
        const int c = tid;
        #pragma unroll 4
        for (int ic = 0; ic < 16; ++ic) {
            const float4 v = *(const float4*)&xbase[(size_t)c*4096 + ic*4];
            const float vv[4] = {v.x, v.y, v.z, v.w};
            #pragma unroll
            for (int u = 0; u < 4; ++u) xs[(ic*4+u)*264 + c] = f2bf(vv[u]);
        }
    }
    __syncthreads();
    #pragma unroll
    for (int u8 = 0; u8 < 8; ++u8)
        *(s16x8*)&xTh[row*256 + cch + u8*8] = *(const s16x8*)&xs[iw*264 + cch + u8*8];
    __syncthreads();
    // phase L
    {
        const int c = tid;
        #pragma unroll 4
        for (int ic = 0; ic < 16; ++ic) {
            const float4 v = *(const float4*)&xbase[(size_t)c*4096 + ic*4];
            const float vv[4] = {v.x, v.y, v.z, v.w};
            #pragma unroll
            for (int u = 0; u < 4; ++u) {
                const unsigned short hi = f2bf(vv[u]);
                xs[(ic*4+u)*264 + c] = f2bf(vv[u] - bf2f(hi));
            }
        }
    }
    __syncthreads();
    #pragma unroll
    for (int u8 = 0; u8 < 8; ++u8)
        *(s16x8*)&xTl[row*256 + cch + u8*8] = *(const s16x8*)&xs[iw*264 + cch + u8*8];
}

// ---------------- Kernel 0b: split w -> wh, wl bf16 ----------------
__global__ __launch_bounds__(256) void k_wsplit(const float* __restrict__ w,
                                                unsigned short* __restrict__ wh,
                                                unsigned short* __restrict__ wl)
{
    const int t4 = blockIdx.x*256 + threadIdx.x;   // 32768 float4s
    const float4 v = *(const float4*)&w[(size_t)t4*4];
    const float vv[4] = {v.x, v.y, v.z, v.w};
    ushort4 hi4, lo4;
    unsigned short* hp = (unsigned short*)&hi4;
    unsigned short* lp = (unsigned short*)&lo4;
    #pragma unroll
    for (int u = 0; u < 4; ++u) {
        hp[u] = f2bf(vv[u]);
        lp[u] = f2bf(vv[u] - bf2f(hp[u]));
    }
    *(ushort4*)&wh[(size_t)t4*4] = hi4;
    *(ushort4*)&wl[(size_t)t4*4] = lo4;
}

// ---------------- Kernel 1: qkv = W.X via 3-term hi/lo bf16 MFMA ----------------
// C[o][col] (col=(n,i), n-major), M=512, N=16384, K=3x256.
// grid (4 o-blocks, 128 col-blocks), 256 thr, 128x128 tile, BK=64.
// Staging: reg-stage (global_load_dwordx4 -> ds_write_b128), LDS rows padded to 72.
__global__ __launch_bounds__(256) void k_qkv_mfma(const unsigned short* __restrict__ wh,
                                                  const unsigned short* __restrict__ wl,
                                                  const unsigned short* __restrict__ xTh,
                                                  const unsigned short* __restrict__ xTl,
                                                  float* __restrict__ qkv)
{
    __shared__ unsigned short As[128*72];   // 18,432 B
    __shared__ unsigned short Bs[128*72];
    const int o0   = blockIdx.x * 128;
    const int col0 = blockIdx.y * 128;
    const int tid = threadIdx.x;
    const int w = tid >> 6, l = tid & 63, lb = l & 15, h = l >> 4;

    f32x4 acc[4][4];
    #pragma unroll
    for (int m = 0; m < 4; ++m)
        #pragma unroll
        for (int nn = 0; nn < 4; ++nn) { acc[m][nn][0]=0.f; acc[m][nn][1]=0.f; acc[m][nn][2]=0.f; acc[m][nn][3]=0.f; }

    const int oq = (w >> 1) * 64, cq = (w & 1) * 64;

    for (int step = 0; step < 12; ++step) {
        const int seg = step >> 2, kk = (step & 3) * 64;
        const unsigned short* Ap = (seg == 1) ? wl  : wh;
        const unsigned short* Bp = (seg == 2) ? xTl : xTh;
        // issue global loads to registers (no LDS hazard yet)
        int4 aR[4], bR[4];
        #pragma unroll
        for (int q = 0; q < 4; ++q) {
            const int f = q*256 + tid;              // 0..1023
            const int row = f >> 3, c16 = (f & 7) * 8;
            aR[q] = *(const int4*)(Ap + (size_t)(o0  + row)*256 + kk + c16);
            bR[q] = *(const int4*)(Bp + (size_t)(col0 + row)*256 + kk + c16);
        }
        __syncthreads();   // previous step's ds_reads complete
        #pragma unroll
        for (int q = 0; q < 4; ++q) {
            const int f = q*256 + tid;
            const int row = f >> 3, c16 = (f & 7) * 8;
            *(int4*)&As[row*72 + c16] = aR[q];
            *(int4*)&Bs[row*72 + c16] = bR[q];
        }
        __syncthreads();   // writes visible
        #pragma unroll
        for (int ks = 0; ks < 64; ks += 32) {
            s16x8 a[4], b[4];
            #pragma unroll
            for (int m = 0; m < 4; ++m) a[m] = *(const s16x8*)&As[(oq + m*16 + lb)*72 + ks + h*8];
            #pragma unroll
            for (int nn = 0; nn < 4; ++nn) b[nn] = *(const s16x8*)&Bs[(cq + nn*16 + lb)*72 + ks + h*8];
            #pragma unroll
            for (int m = 0; m < 4; ++m)
                #pragma unroll
                for (int nn = 0; nn < 4; ++nn)
                    acc[m][nn] = __builtin_amdgcn_mfma_f32_16x16x32_bf16(a[m], b[nn], acc[m][nn], 0,0,0);
        }
    }
    // epilogue: C row o = o0+oq+m*16+h*4+r ; col = col0+cq+nn*16+lb -> qkv[n][o][i]
    #pragma unroll
    for (int m = 0; m < 4; ++m)
        #pragma unroll
        for (int nn = 0; nn < 4; ++nn) {
            const int col = col0 + cq + nn*16 + lb;
            float* dst = qkv + (size_t)(col >> 6)*32768 + (col & 63);
            #pragma unroll
            for (int r = 0; r < 4; ++r) {
                const int o = o0 + oq + m*16 + h*4 + r;
                dst[(size_t)o*64] = acc[m][nn][r];
            }
        }
}

// ---------------- Kernel 2: bn1 stats -> folded affine a1,b1 ----------------
__global__ __launch_bounds__(256) void k_bn1(const float* __restrict__ qkv,
                                             const float* __restrict__ gamma,
                                             const float* __restrict__ beta,
                                             float* __restrict__ a1, float* __restrict__ b1)
{
    const int o = blockIdx.x;
    const int tid = threadIdx.x;
    float s = 0.f, s2 = 0.f;
    const float* base = qkv + (size_t)o*64;
    for (int t = tid; t < 16384; t += 256) {
        const int n = t >> 6, i = t & 63;
        const float v = base[(size_t)n*32768 + i];
        s += v; s2 += v*v;
    }
    __shared__ float rs[4], rs2[4];
    #pragma unroll
    for (int off = 32; off; off >>= 1) { s += __shfl_down(s, off); s2 += __shfl_down(s2, off); }
    if ((tid & 63) == 0) { rs[tid>>6] = s; rs2[tid>>6] = s2; }
    __syncthreads();
    if (tid == 0) {
        const float S  = rs[0]+rs[1]+rs[2]+rs[3];
        const float S2 = rs2[0]+rs2[1]+rs2[2]+rs2[3];
        const float mean = S * (1.f/16384.f);
        const float var  = S2 * (1.f/16384.f) - mean*mean;
        const float A = gamma[o] * rsqrtf(var + 1e-5f);
        a1[o] = A;
        b1[o] = beta[o] - mean*A;
    }
}

// ---------------- Kernels 3/5: per-(n,g) MFMA core (verified round 3) ----------------
template<int PASSB>
__global__ __launch_bounds__(256) void k_pass2(const float* __restrict__ qkv,
    const float* __restrict__ a1, const float* __restrict__ b1,
    const float* __restrict__ rel_emb,
    float* __restrict__ p2, const float* __restrict__ a2,
    float* __restrict__ attnW, float* __restrict__ attneW)
{
    extern __shared__ char sm[];
    unsigned short (* const qkT)[32]    = (unsigned short(*)[32])(sm);
    unsigned short (* const rembTq)[32] = (unsigned short(*)[32])(sm + 4096);
    unsigned short (* const rembTk)[32] = (unsigned short(*)[32])(sm + 12288);
    unsigned short (* const PSt)[136]   = (unsigned short(*)[136])(sm);
    unsigned short (* const qeT)[72]    = (unsigned short(*)[72])(sm + 20480);
    unsigned short (* const pT)[72]     = (unsigned short(*)[72])(sm + 20480);
    unsigned short (* const keT)[72]    = (unsigned short(*)[72])(sm + 29696);
    unsigned short (* const rembV)[136] = (unsigned short(*)[136])(sm + 29696);
    unsigned short (* const vbL)[72]    = (unsigned short(*)[72])(sm + 34048);
    float* const red = (float*)(sm + 38912);

    const int bx = blockIdx.x, n = bx >> 4, g = bx & 15;
    const int tid = threadIdx.x;
    const int w = tid >> 6, l = tid & 63, lb = l & 15, h = l >> 4;

    {
        int4 z4; z4.x = z4.y = z4.z = z4.w = 0;
        int4* dst = (int4*)(sm + 4096);
        for (int t = tid; t < 1024; t += 256) dst[t] = z4;
    }
    __syncthreads();

    {   // qkT staging
        const int a = tid & 63, c0 = (tid >> 6) * 4;
        unsigned long long pk = 0;
        #pragma unroll
        for (int u = 0; u < 4; ++u) {
            const int o = g*32 + c0 + u;
            const float val = a1[o] * qkv[(size_t)n*32768 + (size_t)o*64 + a] + b1[o];
            pk |= (unsigned long long)f2bf(val) << (16*u);
        }
        *(unsigned long long*)&qkT[a][c0] = pk;
        *(unsigned long long*)&qkT[a][16 + c0] = 0ull;
    }
    {   // rembTq / rembTk staging
        const int d = tid >> 1, half = tid & 1;
        if (d < 127) {
            if (half == 0) {
                unsigned long long p0 = 0, p1 = 0;
                #pragma unroll
                for (int c = 0; c < 4; ++c) p0 |= (unsigned long long)f2bf(rel_emb[c*127 + d]) << (16*c);
                #pragma unroll
                for (int c = 0; c < 4; ++c) p1 |= (unsigned long long)f2bf(rel_emb[(4+c)*127 + d]) << (16*c);
                *(unsigned long long*)&rembTq[d][0] = p0;
                *(unsigned long long*)&rembTq[d][4] = p1;
            } else {
                unsigned long long p0 = 0, p1 = 0;
                #pragma unroll
                for (int c = 0; c < 4; ++c) p0 |= (unsigned long long)f2bf(rel_emb[(8+c)*127 + d]) << (16*c);
                #pragma unroll
                for (int c = 0; c < 4; ++c) p1 |= (unsigned long long)f2bf(rel_emb[(12+c)*127 + d]) << (16*c);
                *(unsigned long long*)&rembTk[d][8] = p0;
                *(unsigned long long*)&rembTk[d][12] = p1;
            }
        }
    }
    float vreg[4] = {0,0,0,0};
    float evreg[8] = {0,0,0,0,0,0,0,0};
    if (PASSB) {
        const int cv = tid >> 4, ap = (tid & 15) * 4;
        const int o = g*32 + 16 + cv;
        const float A = a1[o], Bc = b1[o];
        const float4 vv = *(const float4*)&qkv[(size_t)n*32768 + (size_t)o*64 + ap];
        vreg[0] = A*vv.x + Bc; vreg[1] = A*vv.y + Bc;
        vreg[2] = A*vv.z + Bc; vreg[3] = A*vv.w + Bc;
        const int d0 = (tid & 15) * 8;
        #pragma unroll
        for (int kk = 0; kk < 8; ++kk)
            evreg[kk] = (d0 + kk < 127) ? rel_emb[(16+cv)*127 + d0 + kk] : 0.f;
    }
    __syncthreads();

    float sqe=0.f, s2qe=0.f, ske=0.f, s2ke=0.f;
    {
        const int a0 = w*16;
        const s16x8 afr = *(const s16x8*)&qkT[a0 + lb][h*8];
        #pragma unroll
        for (int dt = 0; dt < 8; ++dt) {
            const s16x8 bq = *(const s16x8*)&rembTq[dt*16 + lb][h*8];
            const s16x8 bk = *(const s16x8*)&rembTk[dt*16 + lb][h*8];
            f32x4 zz = {0.f,0.f,0.f,0.f};
            f32x4 cq = __builtin_amdgcn_mfma_f32_16x16x32_bf16(afr, bq, zz, 0,0,0);
            f32x4 ck = __builtin_amdgcn_mfma_f32_16x16x32_bf16(afr, bk, zz, 0,0,0);
            const int d = dt*16 + lb;
            #pragma unroll
            for (int r = 0; r < 4; ++r) {
                const int a = a0 + h*4 + r;
                const int i = a + 63 - d;
                if (i >= 0 && i < 64) {
                    const float vq = cq[r], vk = ck[r];
                    qeT[i][a] = f2bf(vq);
                    keT[i][a] = f2bf(vk);
                    if (!PASSB) { sqe += vq; s2qe += vq*vq; ske += vk; s2ke += vk*vk; }
                }
            }
        }
    }
    __syncthreads();

    const int i0 = w*16;
    f32x4 acc[4];
    #pragma unroll
    for (int jt = 0; jt < 4; ++jt) { acc[jt][0]=0.f; acc[jt][1]=0.f; acc[jt][2]=0.f; acc[jt][3]=0.f; }
    #pragma unroll
    for (int kc = 0; kc < 2; ++kc) {
        const s16x8 aq = *(const s16x8*)&qeT[i0 + lb][kc*32 + h*8];
        #pragma unroll
        for (int jt = 0; jt < 4; ++jt) {
            const s16x8 bk2 = *(const s16x8*)&keT[jt*16 + lb][kc*32 + h*8];
            acc[jt] = __builtin_amdgcn_mfma_f32_16x16x32_bf16(aq, bk2, acc[jt], 0,0,0);
        }
    }

    if (!PASSB) {
        float sqk=0.f, s2qk=0.f;
        #pragma unroll
        for (int jt = 0; jt < 4; ++jt)
            #pragma unroll
            for (int r = 0; r < 4; ++r) { const float q_ = acc[jt][r]; sqk += q_; s2qk += q_*q_; }
        float vals[6] = {sqk, s2qk, sqe, s2qe, ske, s2ke};
        #pragma unroll
        for (int q = 0; q < 6; ++q) {
            float v = vals[q];
            #pragma unroll
            for (int off = 32; off; off >>= 1) v += __shfl_xor(v, off);
            if (l == 0) red[w*6 + q] = v;
        }
        __syncthreads();
        if (tid < 6) p2[(size_t)bx*6 + tid] = red[tid] + red[6+tid] + red[12+tid] + red[18+tid];
        return;
    }

    {
        int4 z4; z4.x=z4.y=z4.z=z4.w=0;
        int4* dst = (int4*)sm;
        for (int t = tid; t < 1088; t += 256) dst[t] = z4;
    }

    const float c_qk = a2[g], c_qe = a2[16+g], c_ke = a2[32+g];
    float p[4][4];
    #pragma unroll
    for (int jt = 0; jt < 4; ++jt) {
        const unsigned long long q4 = *(const unsigned long long*)&qeT[jt*16 + lb][i0 + 4*h];
        const unsigned long long k4 = *(const unsigned long long*)&keT[jt*16 + lb][i0 + 4*h];
        #pragma unroll
        for (int r = 0; r < 4; ++r) {
            p[jt][r] = c_qk*acc[jt][r]
                     + c_qe*bf2f((unsigned short)(q4 >> (16*r)))
                     + c_ke*bf2f((unsigned short)(k4 >> (16*r)));
        }
    }
    #pragma unroll
    for (int r = 0; r < 4; ++r) {
        float m = fmaxf(fmaxf(p[0][r], p[1][r]), fmaxf(p[2][r], p[3][r]));
        #pragma unroll
        for (int mk = 8; mk; mk >>= 1) m = fmaxf(m, __shfl_xor(m, mk));
        float s = 0.f;
        #pragma unroll
        for (int jt = 0; jt < 4; ++jt) { p[jt][r] = __expf(p[jt][r] - m); s += p[jt][r]; }
        #pragma unroll
        for (int mk = 8; mk; mk >>= 1) s += __shfl_xor(s, mk);
        const float inv = 1.f / s;
        #pragma unroll
        for (int jt = 0; jt < 4; ++jt) p[jt][r] *= inv;
    }
    __syncthreads();

    #pragma unroll
    for (int jt = 0; jt < 4; ++jt)
        #pragma unroll
        for (int r = 0; r < 4; ++r) {
            const int i = i0 + 4*h + r, j = jt*16 + lb;
            const unsigned short pb = f2bf(p[jt][r]);
            pT[i][j] = pb;
            PSt[i][i + 63 - j] = pb;
        }
    {
        const int cv = tid >> 4, ap = (tid & 15)*4;
        unsigned long long pk = 0;
        #pragma unroll
        for (int u = 0; u < 4; ++u) pk |= (unsigned long long)f2bf(vreg[u]) << (16*u);
        *(unsigned long long*)&vbL[cv][ap] = pk;
        const int d0 = (tid & 15)*8;
        unsigned long long e0 = 0, e1 = 0;
        #pragma unroll
        for (int u = 0; u < 4; ++u) e0 |= (unsigned long long)f2bf(evreg[u]) << (16*u);
        #pragma unroll
        for (int u = 0; u < 4; ++u) e1 |= (unsigned long long)f2bf(evreg[4+u]) << (16*u);
        *(unsigned long long*)&rembV[cv][d0]   = e0;
        *(unsigned long long*)&rembV[cv][d0+4] = e1;
    }
    __syncthreads();

    f32x4 accA = {0.f,0.f,0.f,0.f}, accE = {0.f,0.f,0.f,0.f};
    #pragma unroll
    for (int kc = 0; kc < 2; ++kc) {
        const s16x8 av = *(const s16x8*)&vbL[lb][kc*32 + h*8];
        const s16x8 bp = *(const s16x8*)&pT[i0 + lb][kc*32 + h*8];
        accA = __builtin_amdgcn_mfma_f32_16x16x32_bf16(av, bp, accA, 0,0,0);
    }
    #pragma unroll
    for (int kc = 0; kc < 4; ++kc) {
        const s16x8 ae = *(const s16x8*)&rembV[lb][kc*32 + h*8];
        const s16x8 bs = *(const s16x8*)&PSt[i0 + lb][kc*32 + h*8];
        accE = __builtin_amdgcn_mfma_f32_16x16x32_bf16(ae, bs, accE, 0,0,0);
    }
    float* aw = attnW  + ((size_t)n*16 + g)*1024;
    float* ew = attneW + ((size_t)n*16 + g)*1024;
    #pragma unroll
    for (int r = 0; r < 4; ++r) {
        aw[(4*h + r)*64 + i0 + lb] = accA[r];
        ew[(4*h + r)*64 + i0 + lb] = accE[r];
    }
}

// ---------------- Kernel 4: bn2 finalize (12 blocks x 4 waves = 48 ch) ----------------
__global__ __launch_bounds__(256) void k_bn2(const float* __restrict__ p2,
                                             const float* __restrict__ gamma2,
                                             float* __restrict__ a2)
{
    const int ch = blockIdx.x*4 + (threadIdx.x >> 6);   // 0..47
    const int l = threadIdx.x & 63;
    const int kind = ch >> 4, g = ch & 15;
    float s = 0.f, s2 = 0.f;
    #pragma unroll
    for (int q = 0; q < 4; ++q) {
        const int nn = q*64 + l;
        const float* p = p2 + ((size_t)nn*16 + g)*6 + 2*kind;
        s += p[0]; s2 += p[1];
    }
    #pragma unroll
    for (int off = 32; off; off >>= 1) { s += __shfl_down(s, off); s2 += __shfl_down(s2, off); }
    if (l == 0) {
        const float mean = s * (1.f/1048576.f);
        const float var  = s2 * (1.f/1048576.f) - mean*mean;
        a2[ch] = gamma2[ch] * rsqrtf(var + 1e-5f);
    }
}

// ---------------- Kernel 6: bn3 stats -> a3,b3 ----------------
__global__ __launch_bounds__(256) void k_bn3(const float* __restrict__ attnW,
                                             const float* __restrict__ attneW,
                                             const float* __restrict__ gamma,
                                             const float* __restrict__ beta,
                                             float* __restrict__ a3, float* __restrict__ b3)
{
    const int o = blockIdx.x;
    const int g = o >> 5, rem = o & 31, c = rem >> 1, sflag = rem & 1;
    const float* src = (sflag ? attneW : attnW) + (size_t)g*1024 + (size_t)c*64;
    const int tid = threadIdx.x;
    float s = 0.f, s2 = 0.f;
    for (int t = tid; t < 16384; t += 256) {
        const int n = t >> 6, i = t & 63;
        const float v = src[(size_t)n*16384 + i];
        s += v; s2 += v*v;
    }
    __shared__ float rs[4], rs2[4];
    #pragma unroll
    for (int off = 32; off; off >>= 1) { s += __shfl_down(s, off); s2 += __shfl_down(s2, off); }
    if ((tid & 63) == 0) { rs[tid>>6] = s; rs2[tid>>6] = s2; }
    __syncthreads();
    if (tid == 0) {
        const float S  = rs[0]+rs[1]+rs[2]+rs[3];
        const float S2 = rs2[0]+rs2[1]+rs2[2]+rs2[3];
        const float mean = S * (1.f/16384.f);
        const float var  = S2 * (1.f/16384.f) - mean*mean;
        const float A = gamma[o] * rsqrtf(var + 1e-5f);
        a3[o] = A;
        b3[o] = beta[o] - mean*A;
    }
}

// ---------------- Kernel 7: apply bn3, sum channel pairs, transpose ----------------
__global__ __launch_bounds__(256) void k_out(const float* __restrict__ attnW,
                                             const float* __restrict__ attneW,
                                             const float* __restrict__ a3,
                                             const float* __restrict__ b3,
                                             float* __restrict__ out)
{
    const int idx = blockIdx.x*256 + threadIdx.x;
    const int i  = idx & 63;
    const int h  = (idx >> 6) & 63;
    const int oc = (idx >> 12) & 255;
    const int b  = idx >> 20;
    const int g = oc >> 4, c = oc & 15;
    const int n = b*64 + h;
    const size_t src = ((size_t)n*16 + g)*1024 + (size_t)c*64 + i;
    const int o0 = g*32 + 2*c;
    out[idx] = a3[o0]*attnW[src] + a3[o0+1]*attneW[src] + (b3[o0] + b3[o0+1]);
}

extern "C" void kernel_launch(void* const* d_in, const int* in_sizes, int n_in,
                              void* d_out, int out_size, void* d_ws, size_t ws_size,
                              hipStream_t stream) {
    const float* x    = (const float*)d_in[0];
    const float* w    = (const float*)d_in[1];
    const float* g1   = (const float*)d_in[2];
    const float* be1  = (const float*)d_in[3];
    const float* remb = (const float*)d_in[4];
    const float* g2   = (const float*)d_in[5];
    const float* g3   = (const float*)d_in[7];
    const float* be3  = (const float*)d_in[8];
    float* out = (float*)d_out;
    float* ws  = (float*)d_ws;

    float* qkv   = ws + OFF_QKV;
    float* a1    = ws + OFF_A1;
    float* b1    = ws + OFF_B1;
    float* p2    = ws + OFF_P2;
    float* a2    = ws + OFF_A2;
    float* attnW = ws + OFF_ATTN;
    float* attneW= ws + OFF_ATTNE;
    float* a3    = ws + OFF_A3;
    float* b3    = ws + OFF_B3;
    unsigned short* xTh = (unsigned short*)(ws + OFF_XTH);
    unsigned short* xTl = (unsigned short*)(ws + OFF_XTL);
    unsigned short* wh  = (unsigned short*)(ws + OFF_WH);
    unsigned short* wl  = (unsigned short*)(ws + OFF_WL);

    const int SHM = 39040;
    k_split<<<256, 256, 0, stream>>>(x, xTh, xTl);
    k_wsplit<<<128, 256, 0, stream>>>(w, wh, wl);
    k_qkv_mfma<<<dim3(4, 128), 256, 0, stream>>>(wh, wl, xTh, xTl, qkv);
    k_bn1<<<512, 256, 0, stream>>>(qkv, g1, be1, a1, b1);
    k_pass2<0><<<4096, 256, SHM, stream>>>(qkv, a1, b1, remb, p2, nullptr, nullptr, nullptr);
    k_bn2<<<12, 256, 0, stream>>>(p2, g2, a2);
    k_pass2<1><<<4096, 256, SHM, stream>>>(qkv, a1, b1, remb, nullptr, a2, attnW, attneW);
    k_bn3<<<512, 256, 0, stream>>>(attnW, attneW, g3, be3, a3, b3);
    k_out<<<16384, 256, 0, stream>>>(attnW, attneW, a3, b3, out);
}

// Round 7
// 171.828 us; speedup vs baseline: 2.5154x; 1.1678x over previous
//
#include <hip/hip_runtime.h>
#include <hip/hip_bf16.h>

typedef short s16x8 __attribute__((ext_vector_type(8)));
typedef float f32x4 __attribute__((ext_vector_type(4)));

static __device__ __forceinline__ unsigned short f2bf(float f){
    unsigned int u = __float_as_uint(f);
    u += 0x7fffu + ((u >> 16) & 1u);
    return (unsigned short)(u >> 16);
}
static __device__ __forceinline__ float bf2f(unsigned short h){
    return __uint_as_float(((unsigned int)h) << 16);
}

// ---------------- workspace layout (float offsets) ----------------
static const size_t OFF_QKV   = 0;
static const size_t OFF_A1    = 8388608;
static const size_t OFF_B1    = 8389120;
static const size_t OFF_P2    = 8389632;
static const size_t OFF_A2    = 8414208;
static const size_t OFF_ATTN  = 8414272;
static const size_t OFF_ATTNE = 12608576;
static const size_t OFF_A3    = 16802880;
static const size_t OFF_B3    = 16803392;
// transient (pre-passB) overlays inside the attnW/attneW span:
static const size_t OFF_XTH = OFF_ATTN;               // bf16[16384][256] = 2,097,152 floats
static const size_t OFF_WH  = OFF_ATTN + 4194304;     // bf16[512][256]  = 65,536 floats
static const size_t OFF_WL  = OFF_ATTN + 4259840;     // bf16[512][256]  = 65,536 floats

// ---------------- Kernel 0a: bf16 round + transpose x -> xT_hi [(n,i)][c] ----------------
__global__ __launch_bounds__(256) void k_split(const float* __restrict__ x,
                                               unsigned short* __restrict__ xTh)
{
    __shared__ unsigned short xs[64*264];   // 33,792 B
    const int n = blockIdx.x;               // 0..255 = (b,h)
    const int b = n >> 6, h = n & 63;
    const float* xbase = x + (size_t)b*256*4096 + (size_t)h*64;  // [c*4096 + i]
    const int tid = threadIdx.x;
    const int iw = tid >> 2, cch = (tid & 3) * 64;
    const size_t row = (size_t)n*64 + iw;
    {
        const int c = tid;
        #pragma unroll 4
        for (int ic = 0; ic < 16; ++ic) {
            const float4 v = *(const float4*)&xbase[(size_t)c*4096 + ic*4];
            const float vv[4] = {v.x, v.y, v.z, v.w};
            #pragma unroll
            for (int u = 0; u < 4; ++u) xs[(ic*4+u)*264 + c] = f2bf(vv[u]);
        }
    }
    __syncthreads();
    #pragma unroll
    for (int u8 = 0; u8 < 8; ++u8)
        *(s16x8*)&xTh[row*256 + cch + u8*8] = *(const s16x8*)&xs[iw*264 + cch + u8*8];
}

// ---------------- Kernel 0b: split w -> wh, wl bf16 ----------------
__global__ __launch_bounds__(256) void k_wsplit(const float* __restrict__ w,
                                                unsigned short* __restrict__ wh,
                                                unsigned short* __restrict__ wl)
{
    const int t4 = blockIdx.x*256 + threadIdx.x;   // 32768 float4s
    const float4 v = *(const float4*)&w[(size_t)t4*4];
    const float vv[4] = {v.x, v.y, v.z, v.w};
    ushort4 hi4, lo4;
    unsigned short* hp = (unsigned short*)&hi4;
    unsigned short* lp = (unsigned short*)&lo4;
    #pragma unroll
    for (int u = 0; u < 4; ++u) {
        hp[u] = f2bf(vv[u]);
        lp[u] = f2bf(vv[u] - bf2f(hp[u]));
    }
    *(ushort4*)&wh[(size_t)t4*4] = hi4;
    *(ushort4*)&wl[(size_t)t4*4] = lo4;
}

// ---------------- Kernel 1: qkv = (wh+wl).xh via MFMA, 2-phase pipelined ----------------
// M=512 (o), N=16384 (col=(n,i)), K=256. 128x128 tile, BK=32, 8 steps.
// Per step: 12 ds_read_b128, 32 MFMA (hi & lo accumulate into the SAME acc).
// Epilogue: LDS-bounce -> fully coalesced float4 stores.
__global__ __launch_bounds__(256) void k_qkv_mfma(const unsigned short* __restrict__ wh,
                                                  const unsigned short* __restrict__ wl,
                                                  const unsigned short* __restrict__ xTh,
                                                  float* __restrict__ qkv)
{
    __shared__ int4 smem4[2176];            // 34,816 B
    unsigned short* const Ah = (unsigned short*)smem4;                 // [128][40]
    unsigned short* const Al = (unsigned short*)((char*)smem4 + 10240);
    unsigned short* const Bh = (unsigned short*)((char*)smem4 + 20480);
    float* const Cl = (float*)smem4;                                   // [128][68] epilogue overlay
    const int o0   = blockIdx.x * 128;
    const int col0 = blockIdx.y * 128;
    const int tid = threadIdx.x;
    const int w = tid >> 6, l = tid & 63, lb = l & 15, h = l >> 4;
    const int oq = (w >> 1) * 64, cq = (w & 1) * 64;

    f32x4 acc[4][4];
    #pragma unroll
    for (int m = 0; m < 4; ++m)
        #pragma unroll
        for (int nn = 0; nn < 4; ++nn) { acc[m][nn][0]=0.f; acc[m][nn][1]=0.f; acc[m][nn][2]=0.f; acc[m][nn][3]=0.f; }

    const int fr0 = tid >> 2, fc0 = (tid & 3) * 8;           // q=0 chunk
    const int fr1 = (256 + tid) >> 2, fc1 = fc0;             // q=1 chunk (row+64)
    int4 rAh[2], rAl[2], rBh[2];
    // prologue: step 0
    rAh[0] = *(const int4*)(wh  + (size_t)(o0  +fr0)*256 + fc0);
    rAl[0] = *(const int4*)(wl  + (size_t)(o0  +fr0)*256 + fc0);
    rBh[0] = *(const int4*)(xTh + (size_t)(col0+fr0)*256 + fc0);
    rAh[1] = *(const int4*)(wh  + (size_t)(o0  +fr1)*256 + fc1);
    rAl[1] = *(const int4*)(wl  + (size_t)(o0  +fr1)*256 + fc1);
    rBh[1] = *(const int4*)(xTh + (size_t)(col0+fr1)*256 + fc1);
    *(int4*)&Ah[fr0*40 + fc0] = rAh[0]; *(int4*)&Al[fr0*40 + fc0] = rAl[0]; *(int4*)&Bh[fr0*40 + fc0] = rBh[0];
    *(int4*)&Ah[fr1*40 + fc1] = rAh[1]; *(int4*)&Al[fr1*40 + fc1] = rAl[1]; *(int4*)&Bh[fr1*40 + fc1] = rBh[1];

    for (int step = 0; step < 8; ++step) {
        __syncthreads();                       // LDS tile ready
        if (step < 7) {                        // prefetch next tile into regs
            const int kk = (step+1)*32;
            rAh[0] = *(const int4*)(wh  + (size_t)(o0  +fr0)*256 + kk + fc0);
            rAl[0] = *(const int4*)(wl  + (size_t)(o0  +fr0)*256 + kk + fc0);
            rBh[0] = *(const int4*)(xTh + (size_t)(col0+fr0)*256 + kk + fc0);
            rAh[1] = *(const int4*)(wh  + (size_t)(o0  +fr1)*256 + kk + fc1);
            rAl[1] = *(const int4*)(wl  + (size_t)(o0  +fr1)*256 + kk + fc1);
            rBh[1] = *(const int4*)(xTh + (size_t)(col0+fr1)*256 + kk + fc1);
        }
        s16x8 ah[4], al[4], bf[4];
        #pragma unroll
        for (int m = 0; m < 4; ++m)  ah[m] = *(const s16x8*)&Ah[(oq + m*16 + lb)*40 + h*8];
        #pragma unroll
        for (int m = 0; m < 4; ++m)  al[m] = *(const s16x8*)&Al[(oq + m*16 + lb)*40 + h*8];
        #pragma unroll
        for (int nn = 0; nn < 4; ++nn) bf[nn] = *(const s16x8*)&Bh[(cq + nn*16 + lb)*40 + h*8];
        #pragma unroll
        for (int m = 0; m < 4; ++m)
            #pragma unroll
            for (int nn = 0; nn < 4; ++nn)
                acc[m][nn] = __builtin_amdgcn_mfma_f32_16x16x32_bf16(ah[m], bf[nn], acc[m][nn], 0,0,0);
        #pragma unroll
        for (int m = 0; m < 4; ++m)
            #pragma unroll
            for (int nn = 0; nn < 4; ++nn)
                acc[m][nn] = __builtin_amdgcn_mfma_f32_16x16x32_bf16(al[m], bf[nn], acc[m][nn], 0,0,0);
        __syncthreads();                       // ds_reads done before overwrite
        if (step < 7) {
            *(int4*)&Ah[fr0*40 + fc0] = rAh[0]; *(int4*)&Al[fr0*40 + fc0] = rAl[0]; *(int4*)&Bh[fr0*40 + fc0] = rBh[0];
            *(int4*)&Ah[fr1*40 + fc1] = rAh[1]; *(int4*)&Al[fr1*40 + fc1] = rAl[1]; *(int4*)&Bh[fr1*40 + fc1] = rBh[1];
        }
    }

    // epilogue: coalesce through LDS. half=0 -> cols col0..+63 (waves cq=0), half=1 -> +64..127.
    const int orow = tid >> 1, ic = (tid & 1) * 32;
    #pragma unroll
    for (int half = 0; half < 2; ++half) {
        __syncthreads();
        if ((w & 1) == half) {
            #pragma unroll
            for (int m = 0; m < 4; ++m)
                #pragma unroll
                for (int nn = 0; nn < 4; ++nn)
                    #pragma unroll
                    for (int r = 0; r < 4; ++r)
                        Cl[(oq + m*16 + h*4 + r)*68 + nn*16 + lb] = acc[m][nn][r];
        }
        __syncthreads();
        const int nidx = (col0 >> 6) + half;
        float* dst = qkv + (size_t)nidx*32768 + (size_t)(o0 + orow)*64 + ic;
        #pragma unroll
        for (int u = 0; u < 8; ++u)
            *(float4*)&dst[u*4] = *(const float4*)&Cl[orow*68 + ic + u*4];
    }
}

// ---------------- Kernel 2: bn1 stats -> folded affine a1,b1 ----------------
__global__ __launch_bounds__(256) void k_bn1(const float* __restrict__ qkv,
                                             const float* __restrict__ gamma,
                                             const float* __restrict__ beta,
                                             float* __restrict__ a1, float* __restrict__ b1)
{
    const int o = blockIdx.x;
    const int tid = threadIdx.x;
    float s = 0.f, s2 = 0.f;
    const float* base = qkv + (size_t)o*64;
    for (int t = tid; t < 16384; t += 256) {
        const int n = t >> 6, i = t & 63;
        const float v = base[(size_t)n*32768 + i];
        s += v; s2 += v*v;
    }
    __shared__ float rs[4], rs2[4];
    #pragma unroll
    for (int off = 32; off; off >>= 1) { s += __shfl_down(s, off); s2 += __shfl_down(s2, off); }
    if ((tid & 63) == 0) { rs[tid>>6] = s; rs2[tid>>6] = s2; }
    __syncthreads();
    if (tid == 0) {
        const float S  = rs[0]+rs[1]+rs[2]+rs[3];
        const float S2 = rs2[0]+rs2[1]+rs2[2]+rs2[3];
        const float mean = S * (1.f/16384.f);
        const float var  = S2 * (1.f/16384.f) - mean*mean;
        const float A = gamma[o] * rsqrtf(var + 1e-5f);
        a1[o] = A;
        b1[o] = beta[o] - mean*A;
    }
}

// ---------------- Kernels 3/5: per-(n,g) MFMA core (verified round 3) ----------------
template<int PASSB>
__global__ __launch_bounds__(256) void k_pass2(const float* __restrict__ qkv,
    const float* __restrict__ a1, const float* __restrict__ b1,
    const float* __restrict__ rel_emb,
    float* __restrict__ p2, const float* __restrict__ a2,
    float* __restrict__ attnW, float* __restrict__ attneW)
{
    extern __shared__ char sm[];
    unsigned short (* const qkT)[32]    = (unsigned short(*)[32])(sm);
    unsigned short (* const rembTq)[32] = (unsigned short(*)[32])(sm + 4096);
    unsigned short (* const rembTk)[32] = (unsigned short(*)[32])(sm + 12288);
    unsigned short (* const PSt)[136]   = (unsigned short(*)[136])(sm);
    unsigned short (* const qeT)[72]    = (unsigned short(*)[72])(sm + 20480);
    unsigned short (* const pT)[72]     = (unsigned short(*)[72])(sm + 20480);
    unsigned short (* const keT)[72]    = (unsigned short(*)[72])(sm + 29696);
    unsigned short (* const rembV)[136] = (unsigned short(*)[136])(sm + 29696);
    unsigned short (* const vbL)[72]    = (unsigned short(*)[72])(sm + 34048);
    float* const red = (float*)(sm + 38912);

    const int bx = blockIdx.x, n = bx >> 4, g = bx & 15;
    const int tid = threadIdx.x;
    const int w = tid >> 6, l = tid & 63, lb = l & 15, h = l >> 4;

    {
        int4 z4; z4.x = z4.y = z4.z = z4.w = 0;
        int4* dst = (int4*)(sm + 4096);
        for (int t = tid; t < 1024; t += 256) dst[t] = z4;
    }
    __syncthreads();

    {   // qkT staging
        const int a = tid & 63, c0 = (tid >> 6) * 4;
        unsigned long long pk = 0;
        #pragma unroll
        for (int u = 0; u < 4; ++u) {
            const int o = g*32 + c0 + u;
            const float val = a1[o] * qkv[(size_t)n*32768 + (size_t)o*64 + a] + b1[o];
            pk |= (unsigned long long)f2bf(val) << (16*u);
        }
        *(unsigned long long*)&qkT[a][c0] = pk;
        *(unsigned long long*)&qkT[a][16 + c0] = 0ull;
    }
    {   // rembTq / rembTk staging
        const int d = tid >> 1, half = tid & 1;
        if (d < 127) {
            if (half == 0) {
                unsigned long long p0 = 0, p1 = 0;
                #pragma unroll
                for (int c = 0; c < 4; ++c) p0 |= (unsigned long long)f2bf(rel_emb[c*127 + d]) << (16*c);
                #pragma unroll
                for (int c = 0; c < 4; ++c) p1 |= (unsigned long long)f2bf(rel_emb[(4+c)*127 + d]) << (16*c);
                *(unsigned long long*)&rembTq[d][0] = p0;
                *(unsigned long long*)&rembTq[d][4] = p1;
            } else {
                unsigned long long p0 = 0, p1 = 0;
                #pragma unroll
                for (int c = 0; c < 4; ++c) p0 |= (unsigned long long)f2bf(rel_emb[(8+c)*127 + d]) << (16*c);
                #pragma unroll
                for (int c = 0; c < 4; ++c) p1 |= (unsigned long long)f2bf(rel_emb[(12+c)*127 + d]) << (16*c);
                *(unsigned long long*)&rembTk[d][8] = p0;
                *(unsigned long long*)&rembTk[d][12] = p1;
            }
        }
    }
    float vreg[4] = {0,0,0,0};
    float evreg[8] = {0,0,0,0,0,0,0,0};
    if (PASSB) {
        const int cv = tid >> 4, ap = (tid & 15) * 4;
        const int o = g*32 + 16 + cv;
        const float A = a1[o], Bc = b1[o];
        const float4 vv = *(const float4*)&qkv[(size_t)n*32768 + (size_t)o*64 + ap];
        vreg[0] = A*vv.x + Bc; vreg[1] = A*vv.y + Bc;
        vreg[2] = A*vv.z + Bc; vreg[3] = A*vv.w + Bc;
        const int d0 = (tid & 15) * 8;
        #pragma unroll
        for (int kk = 0; kk < 8; ++kk)
            evreg[kk] = (d0 + kk < 127) ? rel_emb[(16+cv)*127 + d0 + kk] : 0.f;
    }
    __syncthreads();

    float sqe=0.f, s2qe=0.f, ske=0.f, s2ke=0.f;
    {
        const int a0 = w*16;
        const s16x8 afr = *(const s16x8*)&qkT[a0 + lb][h*8];
        #pragma unroll
        for (int dt = 0; dt < 8; ++dt) {
            const s16x8 bq = *(const s16x8*)&rembTq[dt*16 + lb][h*8];
            const s16x8 bk = *(const s16x8*)&rembTk[dt*16 + lb][h*8];
            f32x4 zz = {0.f,0.f,0.f,0.f};
            f32x4 cq = __builtin_amdgcn_mfma_f32_16x16x32_bf16(afr, bq, zz, 0,0,0);
            f32x4 ck = __builtin_amdgcn_mfma_f32_16x16x32_bf16(afr, bk, zz, 0,0,0);
            const int d = dt*16 + lb;
            #pragma unroll
            for (int r = 0; r < 4; ++r) {
                const int a = a0 + h*4 + r;
                const int i = a + 63 - d;
                if (i >= 0 && i < 64) {
                    const float vq = cq[r], vk = ck[r];
                    qeT[i][a] = f2bf(vq);
                    keT[i][a] = f2bf(vk);
                    if (!PASSB) { sqe += vq; s2qe += vq*vq; ske += vk; s2ke += vk*vk; }
                }
            }
        }
    }
    __syncthreads();

    const int i0 = w*16;
    f32x4 acc[4];
    #pragma unroll
    for (int jt = 0; jt < 4; ++jt) { acc[jt][0]=0.f; acc[jt][1]=0.f; acc[jt][2]=0.f; acc[jt][3]=0.f; }
    #pragma unroll
    for (int kc = 0; kc < 2; ++kc) {
        const s16x8 aq = *(const s16x8*)&qeT[i0 + lb][kc*32 + h*8];
        #pragma unroll
        for (int jt = 0; jt < 4; ++jt) {
            const s16x8 bk2 = *(const s16x8*)&keT[jt*16 + lb][kc*32 + h*8];
            acc[jt] = __builtin_amdgcn_mfma_f32_16x16x32_bf16(aq, bk2, acc[jt], 0,0,0);
        }
    }

    if (!PASSB) {
        float sqk=0.f, s2qk=0.f;
        #pragma unroll
        for (int jt = 0; jt < 4; ++jt)
            #pragma unroll
            for (int r = 0; r < 4; ++r) { const float q_ = acc[jt][r]; sqk += q_; s2qk += q_*q_; }
        float vals[6] = {sqk, s2qk, sqe, s2qe, ske, s2ke};
        #pragma unroll
        for (int q = 0; q < 6; ++q) {
            float v = vals[q];
            #pragma unroll
            for (int off = 32; off; off >>= 1) v += __shfl_xor(v, off);
            if (l == 0) red[w*6 + q] = v;
        }
        __syncthreads();
        if (tid < 6) p2[(size_t)bx*6 + tid] = red[tid] + red[6+tid] + red[12+tid] + red[18+tid];
        return;
    }

    {
        int4 z4; z4.x=z4.y=z4.z=z4.w=0;
        int4* dst = (int4*)sm;
        for (int t = tid; t < 1088; t += 256) dst[t] = z4;
    }

    const float c_qk = a2[g], c_qe = a2[16+g], c_ke = a2[32+g];
    float p[4][4];
    #pragma unroll
    for (int jt = 0; jt < 4; ++jt) {
        const unsigned long long q4 = *(const unsigned long long*)&qeT[jt*16 + lb][i0 + 4*h];
        const unsigned long long k4 = *(const unsigned long long*)&keT[jt*16 + lb][i0 + 4*h];
        #pragma unroll
        for (int r = 0; r < 4; ++r) {
            p[jt][r] = c_qk*acc[jt][r]
                     + c_qe*bf2f((unsigned short)(q4 >> (16*r)))
                     + c_ke*bf2f((unsigned short)(k4 >> (16*r)));
        }
    }
    #pragma unroll
    for (int r = 0; r < 4; ++r) {
        float m = fmaxf(fmaxf(p[0][r], p[1][r]), fmaxf(p[2][r], p[3][r]));
        #pragma unroll
        for (int mk = 8; mk; mk >>= 1) m = fmaxf(m, __shfl_xor(m, mk));
        float s = 0.f;
        #pragma unroll
        for (int jt = 0; jt < 4; ++jt) { p[jt][r] = __expf(p[jt][r] - m); s += p[jt][r]; }
        #pragma unroll
        for (int mk = 8; mk; mk >>= 1) s += __shfl_xor(s, mk);
        const float inv = 1.f / s;
        #pragma unroll
        for (int jt = 0; jt < 4; ++jt) p[jt][r] *= inv;
    }
    __syncthreads();

    #pragma unroll
    for (int jt = 0; jt < 4; ++jt)
        #pragma unroll
        for (int r = 0; r < 4; ++r) {
            const int i = i0 + 4*h + r, j = jt*16 + lb;
            const unsigned short pb = f2bf(p[jt][r]);
            pT[i][j] = pb;
            PSt[i][i + 63 - j] = pb;
        }
    {
        const int cv = tid >> 4, ap = (tid & 15)*4;
        unsigned long long pk = 0;
        #pragma unroll
        for (int u = 0; u < 4; ++u) pk |= (unsigned long long)f2bf(vreg[u]) << (16*u);
        *(unsigned long long*)&vbL[cv][ap] = pk;
        const int d0 = (tid & 15)*8;
        unsigned long long e0 = 0, e1 = 0;
        #pragma unroll
        for (int u = 0; u < 4; ++u) e0 |= (unsigned long long)f2bf(evreg[u]) << (16*u);
        #pragma unroll
        for (int u = 0; u < 4; ++u) e1 |= (unsigned long long)f2bf(evreg[4+u]) << (16*u);
        *(unsigned long long*)&rembV[cv][d0]   = e0;
        *(unsigned long long*)&rembV[cv][d0+4] = e1;
    }
    __syncthreads();

    f32x4 accA = {0.f,0.f,0.f,0.f}, accE = {0.f,0.f,0.f,0.f};
    #pragma unroll
    for (int kc = 0; kc < 2; ++kc) {
        const s16x8 av = *(const s16x8*)&vbL[lb][kc*32 + h*8];
        const s16x8 bp = *(const s16x8*)&pT[i0 + lb][kc*32 + h*8];
        accA = __builtin_amdgcn_mfma_f32_16x16x32_bf16(av, bp, accA, 0,0,0);
    }
    #pragma unroll
    for (int kc = 0; kc < 4; ++kc) {
        const s16x8 ae = *(const s16x8*)&rembV[lb][kc*32 + h*8];
        const s16x8 bs = *(const s16x8*)&PSt[i0 + lb][kc*32 + h*8];
        accE = __builtin_amdgcn_mfma_f32_16x16x32_bf16(ae, bs, accE, 0,0,0);
    }
    float* aw = attnW  + ((size_t)n*16 + g)*1024;
    float* ew = attneW + ((size_t)n*16 + g)*1024;
    #pragma unroll
    for (int r = 0; r < 4; ++r) {
        aw[(4*h + r)*64 + i0 + lb] = accA[r];
        ew[(4*h + r)*64 + i0 + lb] = accE[r];
    }
}

// ---------------- Kernel 4: bn2 finalize (12 blocks x 4 waves = 48 ch) ----------------
__global__ __launch_bounds__(256) void k_bn2(const float* __restrict__ p2,
                                             const float* __restrict__ gamma2,
                                             float* __restrict__ a2)
{
    const int ch = blockIdx.x*4 + (threadIdx.x >> 6);   // 0..47
    const int l = threadIdx.x & 63;
    const int kind = ch >> 4, g = ch & 15;
    float s = 0.f, s2 = 0.f;
    #pragma unroll
    for (int q = 0; q < 4; ++q) {
        const int nn = q*64 + l;
        const float* p = p2 + ((size_t)nn*16 + g)*6 + 2*kind;
        s += p[0]; s2 += p[1];
    }
    #pragma unroll
    for (int off = 32; off; off >>= 1) { s += __shfl_down(s, off); s2 += __shfl_down(s2, off); }
    if (l == 0) {
        const float mean = s * (1.f/1048576.f);
        const float var  = s2 * (1.f/1048576.f) - mean*mean;
        a2[ch] = gamma2[ch] * rsqrtf(var + 1e-5f);
    }
}

// ---------------- Kernel 6: bn3 stats -> a3,b3 ----------------
__global__ __launch_bounds__(256) void k_bn3(const float* __restrict__ attnW,
                                             const float* __restrict__ attneW,
                                             const float* __restrict__ gamma,
                                             const float* __restrict__ beta,
                                             float* __restrict__ a3, float* __restrict__ b3)
{
    const int o = blockIdx.x;
    const int g = o >> 5, rem = o & 31, c = rem >> 1, sflag = rem & 1;
    const float* src = (sflag ? attneW : attnW) + (size_t)g*1024 + (size_t)c*64;
    const int tid = threadIdx.x;
    float s = 0.f, s2 = 0.f;
    for (int t = tid; t < 16384; t += 256) {
        const int n = t >> 6, i = t & 63;
        const float v = src[(size_t)n*16384 + i];
        s += v; s2 += v*v;
    }
    __shared__ float rs[4], rs2[4];
    #pragma unroll
    for (int off = 32; off; off >>= 1) { s += __shfl_down(s, off); s2 += __shfl_down(s2, off); }
    if ((tid & 63) == 0) { rs[tid>>6] = s; rs2[tid>>6] = s2; }
    __syncthreads();
    if (tid == 0) {
        const float S  = rs[0]+rs[1]+rs[2]+rs[3];
        const float S2 = rs2[0]+rs2[1]+rs2[2]+rs2[3];
        const float mean = S * (1.f/16384.f);
        const float var  = S2 * (1.f/16384.f) - mean*mean;
        const float A = gamma[o] * rsqrtf(var + 1e-5f);
        a3[o] = A;
        b3[o] = beta[o] - mean*A;
    }
}

// ---------------- Kernel 7: apply bn3, sum channel pairs, transpose ----------------
__global__ __launch_bounds__(256) void k_out(const float* __restrict__ attnW,
                                             const float* __restrict__ attneW,
                                             const float* __restrict__ a3,
                                             const float* __restrict__ b3,
                                             float* __restrict__ out)
{
    const int idx = blockIdx.x*256 + threadIdx.x;
    const int i  = idx & 63;
    const int h  = (idx >> 6) & 63;
    const int oc = (idx >> 12) & 255;
    const int b  = idx >> 20;
    const int g = oc >> 4, c = oc & 15;
    const int n = b*64 + h;
    const size_t src = ((size_t)n*16 + g)*1024 + (size_t)c*64 + i;
    const int o0 = g*32 + 2*c;
    out[idx] = a3[o0]*attnW[src] + a3[o0+1]*attneW[src] + (b3[o0] + b3[o0+1]);
}

extern "C" void kernel_launch(void* const* d_in, const int* in_sizes, int n_in,
                              void* d_out, int out_size, void* d_ws, size_t ws_size,
                              hipStream_t stream) {
    const float* x    = (const float*)d_in[0];
    const float* w    = (const float*)d_in[1];
    const float* g1   = (const float*)d_in[2];
    const float* be1  = (const float*)d_in[3];
    const float* remb = (const float*)d_in[4];
    const float* g2   = (const float*)d_in[5];
    const float* g3   = (const float*)d_in[7];
    const float* be3  = (const float*)d_in[8];
    float* out = (float*)d_out;
    float* ws  = (float*)d_ws;

    float* qkv   = ws + OFF_QKV;
    float* a1    = ws + OFF_A1;
    float* b1    = ws + OFF_B1;
    float* p2    = ws + OFF_P2;
    float* a2    = ws + OFF_A2;
    float* attnW = ws + OFF_ATTN;
    float* attneW= ws + OFF_ATTNE;
    float* a3    = ws + OFF_A3;
    float* b3    = ws + OFF_B3;
    unsigned short* xTh = (unsigned short*)(ws + OFF_XTH);
    unsigned short* wh  = (unsigned short*)(ws + OFF_WH);
    unsigned short* wl  = (unsigned short*)(ws + OFF_WL);

    const int SHM = 39040;
    k_split<<<256, 256, 0, stream>>>(x, xTh);
    k_wsplit<<<128, 256, 0, stream>>>(w, wh, wl);
    k_qkv_mfma<<<dim3(4, 128), 256, 0, stream>>>(wh, wl, xTh, qkv);
    k_bn1<<<512, 256, 0, stream>>>(qkv, g1, be1, a1, b1);
    k_pass2<0><<<4096, 256, SHM, stream>>>(qkv, a1, b1, remb, p2, nullptr, nullptr, nullptr);
    k_bn2<<<12, 256, 0, stream>>>(p2, g2, a2);
    k_pass2<1><<<4096, 256, SHM, stream>>>(qkv, a1, b1, remb, nullptr, a2, attnW, attneW);
    k_bn3<<<512, 256, 0, stream>>>(attnW, attneW, g3, be3, a3, b3);
    k_out<<<16384, 256, 0, stream>>>(attnW, attneW, a3, b3, out);
}

// Round 8
// 119.072 us; speedup vs baseline: 3.6299x; 1.4431x over previous
//
#include <hip/hip_runtime.h>
#include <hip/hip_bf16.h>

typedef short s16x8 __attribute__((ext_vector_type(8)));
typedef float f32x4 __attribute__((ext_vector_type(4)));

static __device__ __forceinline__ unsigned short f2bf(float f){
    unsigned int u = __float_as_uint(f);
    u += 0x7fffu + ((u >> 16) & 1u);
    return (unsigned short)(u >> 16);
}
static __device__ __forceinline__ float bf2f(unsigned short h){
    return __uint_as_float(((unsigned int)h) << 16);
}

// ---------------- workspace layout (float offsets) ----------------
// qkv is now bf16[256][512][64]  (occupies 2,097,152 floats of the 8.4M span)
// attnW/attneW are bf16[256][16][16][64] (2,097,152 floats each span kept)
static const size_t OFF_QKV   = 0;
static const size_t OFF_A1    = 8388608;
static const size_t OFF_B1    = 8389120;
static const size_t OFF_P2    = 8389632;
static const size_t OFF_A2    = 8414208;
static const size_t OFF_ATTN  = 8414272;
static const size_t OFF_ATTNE = 12608576;
static const size_t OFF_A3    = 16802880;
static const size_t OFF_B3    = 16803392;
// transient (dead before pass2<1> writes attn/attne):
static const size_t OFF_XTH = OFF_ATTN;               // bf16[16384][256]
static const size_t OFF_WH  = OFF_ATTN + 4194304;     // bf16[512][256]
static const size_t OFF_WL  = OFF_ATTN + 4259840;     // bf16[512][256]

// ---------------- Kernel 0a: bf16 round + transpose x -> xT [(n,i)][c] ----------------
__global__ __launch_bounds__(256) void k_split(const float* __restrict__ x,
                                               unsigned short* __restrict__ xTh)
{
    __shared__ unsigned short xs[64*264];
    const int n = blockIdx.x;
    const int b = n >> 6, h = n & 63;
    const float* xbase = x + (size_t)b*256*4096 + (size_t)h*64;
    const int tid = threadIdx.x;
    const int iw = tid >> 2, cch = (tid & 3) * 64;
    const size_t row = (size_t)n*64 + iw;
    {
        const int c = tid;
        #pragma unroll 4
        for (int ic = 0; ic < 16; ++ic) {
            const float4 v = *(const float4*)&xbase[(size_t)c*4096 + ic*4];
            const float vv[4] = {v.x, v.y, v.z, v.w};
            #pragma unroll
            for (int u = 0; u < 4; ++u) xs[(ic*4+u)*264 + c] = f2bf(vv[u]);
        }
    }
    __syncthreads();
    #pragma unroll
    for (int u8 = 0; u8 < 8; ++u8)
        *(s16x8*)&xTh[row*256 + cch + u8*8] = *(const s16x8*)&xs[iw*264 + cch + u8*8];
}

// ---------------- Kernel 0b: split w -> wh, wl bf16 ----------------
__global__ __launch_bounds__(256) void k_wsplit(const float* __restrict__ w,
                                                unsigned short* __restrict__ wh,
                                                unsigned short* __restrict__ wl)
{
    const int t4 = blockIdx.x*256 + threadIdx.x;
    const float4 v = *(const float4*)&w[(size_t)t4*4];
    const float vv[4] = {v.x, v.y, v.z, v.w};
    ushort4 hi4, lo4;
    unsigned short* hp = (unsigned short*)&hi4;
    unsigned short* lp = (unsigned short*)&lo4;
    #pragma unroll
    for (int u = 0; u < 4; ++u) {
        hp[u] = f2bf(vv[u]);
        lp[u] = f2bf(vv[u] - bf2f(hp[u]));
    }
    *(ushort4*)&wh[(size_t)t4*4] = hi4;
    *(ushort4*)&wl[(size_t)t4*4] = lo4;
}

// ---------------- Kernel 1: qkv(bf16) = (wh+wl).xh via MFMA ----------------
// 512 thr / 8 waves; wave quadrant 64x32 (acc[4][2]); 128x128 tile; BK=32, 8 steps.
// Reg-staged 2-phase; epilogue LDS-bounce -> bf16 coalesced stores.
__global__ __launch_bounds__(512) void k_qkv_mfma(const unsigned short* __restrict__ wh,
                                                  const unsigned short* __restrict__ wl,
                                                  const unsigned short* __restrict__ xTh,
                                                  unsigned short* __restrict__ qkvb)
{
    __shared__ char smraw[34816];
    unsigned short* const Ah = (unsigned short*)smraw;           // [128][40]
    unsigned short* const Al = Ah + 5120;
    unsigned short* const Bh = Al + 5120;
    unsigned short* const Cl = (unsigned short*)smraw;           // [128][136] overlay
    const int o0   = blockIdx.x * 128;
    const int col0 = blockIdx.y * 128;
    const int tid = threadIdx.x;
    const int w = tid >> 6, l = tid & 63, lb = l & 15, h = l >> 4;
    const int oq = (w >> 2) * 64, cq = (w & 3) * 32;

    f32x4 acc[4][2];
    #pragma unroll
    for (int m = 0; m < 4; ++m)
        #pragma unroll
        for (int nn = 0; nn < 2; ++nn) { acc[m][nn][0]=0.f; acc[m][nn][1]=0.f; acc[m][nn][2]=0.f; acc[m][nn][3]=0.f; }

    const int srow = tid >> 2, sc8 = (tid & 3) * 8;   // 1 int4 per panel per thread
    int4 rA, rL, rB;
    rA = *(const int4*)(wh  + (size_t)(o0  +srow)*256 + sc8);
    rL = *(const int4*)(wl  + (size_t)(o0  +srow)*256 + sc8);
    rB = *(const int4*)(xTh + (size_t)(col0+srow)*256 + sc8);
    *(int4*)&Ah[srow*40 + sc8] = rA;
    *(int4*)&Al[srow*40 + sc8] = rL;
    *(int4*)&Bh[srow*40 + sc8] = rB;

    for (int step = 0; step < 8; ++step) {
        __syncthreads();                       // LDS tile ready
        if (step < 7) {
            const int kk = (step+1)*32;
            rA = *(const int4*)(wh  + (size_t)(o0  +srow)*256 + kk + sc8);
            rL = *(const int4*)(wl  + (size_t)(o0  +srow)*256 + kk + sc8);
            rB = *(const int4*)(xTh + (size_t)(col0+srow)*256 + kk + sc8);
        }
        s16x8 ah[4], al[4], bf[2];
        #pragma unroll
        for (int m = 0; m < 4; ++m)  ah[m] = *(const s16x8*)&Ah[(oq + m*16 + lb)*40 + h*8];
        #pragma unroll
        for (int m = 0; m < 4; ++m)  al[m] = *(const s16x8*)&Al[(oq + m*16 + lb)*40 + h*8];
        #pragma unroll
        for (int nn = 0; nn < 2; ++nn) bf[nn] = *(const s16x8*)&Bh[(cq + nn*16 + lb)*40 + h*8];
        #pragma unroll
        for (int m = 0; m < 4; ++m)
            #pragma unroll
            for (int nn = 0; nn < 2; ++nn) {
                acc[m][nn] = __builtin_amdgcn_mfma_f32_16x16x32_bf16(ah[m], bf[nn], acc[m][nn], 0,0,0);
                acc[m][nn] = __builtin_amdgcn_mfma_f32_16x16x32_bf16(al[m], bf[nn], acc[m][nn], 0,0,0);
            }
        __syncthreads();                       // ds_reads done before overwrite
        if (step < 7) {
            *(int4*)&Ah[srow*40 + sc8] = rA;
            *(int4*)&Al[srow*40 + sc8] = rL;
            *(int4*)&Bh[srow*40 + sc8] = rB;
        }
    }

    // epilogue: bf16 through LDS, coalesced 16B stores
    #pragma unroll
    for (int m = 0; m < 4; ++m)
        #pragma unroll
        for (int nn = 0; nn < 2; ++nn)
            #pragma unroll
            for (int r = 0; r < 4; ++r)
                Cl[(oq + m*16 + h*4 + r)*136 + cq + nn*16 + lb] = f2bf(acc[m][nn][r]);
    __syncthreads();
    const int erow = tid >> 2, eseg = (tid & 3) * 16;
    #pragma unroll
    for (int h2 = 0; h2 < 2; ++h2) {
        unsigned short* dst = qkvb + ((size_t)((col0 >> 6) + h2)*512 + (o0 + erow))*64 + eseg;
        *(s16x8*)&dst[0] = *(const s16x8*)&Cl[erow*136 + h2*64 + eseg];
        *(s16x8*)&dst[8] = *(const s16x8*)&Cl[erow*136 + h2*64 + eseg + 8];
    }
}

// ---------------- Kernel 2: bn1 stats (bf16 qkv) -> folded affine a1,b1 ----------------
__global__ __launch_bounds__(256) void k_bn1(const unsigned short* __restrict__ qkvb,
                                             const float* __restrict__ gamma,
                                             const float* __restrict__ beta,
                                             float* __restrict__ a1, float* __restrict__ b1)
{
    const int o = blockIdx.x;
    const int tid = threadIdx.x;
    float s = 0.f, s2 = 0.f;
    for (int t = tid; t < 2048; t += 256) {
        const int n = t >> 3, i8 = (t & 7) * 8;
        const s16x8 v8 = *(const s16x8*)&qkvb[((size_t)n*512 + o)*64 + i8];
        #pragma unroll
        for (int j = 0; j < 8; ++j) {
            const float f = bf2f((unsigned short)v8[j]);
            s += f; s2 += f*f;
        }
    }
    __shared__ float rs[4], rs2[4];
    #pragma unroll
    for (int off = 32; off; off >>= 1) { s += __shfl_down(s, off); s2 += __shfl_down(s2, off); }
    if ((tid & 63) == 0) { rs[tid>>6] = s; rs2[tid>>6] = s2; }
    __syncthreads();
    if (tid == 0) {
        const float S  = rs[0]+rs[1]+rs[2]+rs[3];
        const float S2 = rs2[0]+rs2[1]+rs2[2]+rs2[3];
        const float mean = S * (1.f/16384.f);
        const float var  = S2 * (1.f/16384.f) - mean*mean;
        const float A = gamma[o] * rsqrtf(var + 1e-5f);
        a1[o] = A;
        b1[o] = beta[o] - mean*A;
    }
}

// ---------------- Kernels 3/5: per-(n,g) MFMA core (bf16 qkv/attn I/O) ----------------
template<int PASSB>
__global__ __launch_bounds__(256) void k_pass2(const unsigned short* __restrict__ qkvb,
    const float* __restrict__ a1, const float* __restrict__ b1,
    const float* __restrict__ rel_emb,
    float* __restrict__ p2, const float* __restrict__ a2,
    unsigned short* __restrict__ attnb, unsigned short* __restrict__ attneb)
{
    extern __shared__ char sm[];
    unsigned short (* const qkT)[32]    = (unsigned short(*)[32])(sm);
    unsigned short (* const rembTq)[32] = (unsigned short(*)[32])(sm + 4096);
    unsigned short (* const rembTk)[32] = (unsigned short(*)[32])(sm + 12288);
    unsigned short (* const PSt)[136]   = (unsigned short(*)[136])(sm);
    unsigned short (* const qeT)[72]    = (unsigned short(*)[72])(sm + 20480);
    unsigned short (* const pT)[72]     = (unsigned short(*)[72])(sm + 20480);
    unsigned short (* const keT)[72]    = (unsigned short(*)[72])(sm + 29696);
    unsigned short (* const rembV)[136] = (unsigned short(*)[136])(sm + 29696);
    unsigned short (* const vbL)[72]    = (unsigned short(*)[72])(sm + 34048);
    float* const red = (float*)(sm + 38912);

    const int bx = blockIdx.x, n = bx >> 4, g = bx & 15;
    const int tid = threadIdx.x;
    const int w = tid >> 6, l = tid & 63, lb = l & 15, h = l >> 4;

    {
        int4 z4; z4.x = z4.y = z4.z = z4.w = 0;
        int4* dst = (int4*)(sm + 4096);
        for (int t = tid; t < 1024; t += 256) dst[t] = z4;
    }
    __syncthreads();

    {   // qkT staging (bf16 qkv)
        const int a = tid & 63, c0 = (tid >> 6) * 4;
        unsigned long long pk = 0;
        #pragma unroll
        for (int u = 0; u < 4; ++u) {
            const int o = g*32 + c0 + u;
            const float val = a1[o] * bf2f(qkvb[((size_t)n*512 + o)*64 + a]) + b1[o];
            pk |= (unsigned long long)f2bf(val) << (16*u);
        }
        *(unsigned long long*)&qkT[a][c0] = pk;
        *(unsigned long long*)&qkT[a][16 + c0] = 0ull;
    }
    {   // rembTq / rembTk staging
        const int d = tid >> 1, half = tid & 1;
        if (d < 127) {
            if (half == 0) {
                unsigned long long p0 = 0, p1 = 0;
                #pragma unroll
                for (int c = 0; c < 4; ++c) p0 |= (unsigned long long)f2bf(rel_emb[c*127 + d]) << (16*c);
                #pragma unroll
                for (int c = 0; c < 4; ++c) p1 |= (unsigned long long)f2bf(rel_emb[(4+c)*127 + d]) << (16*c);
                *(unsigned long long*)&rembTq[d][0] = p0;
                *(unsigned long long*)&rembTq[d][4] = p1;
            } else {
                unsigned long long p0 = 0, p1 = 0;
                #pragma unroll
                for (int c = 0; c < 4; ++c) p0 |= (unsigned long long)f2bf(rel_emb[(8+c)*127 + d]) << (16*c);
                #pragma unroll
                for (int c = 0; c < 4; ++c) p1 |= (unsigned long long)f2bf(rel_emb[(12+c)*127 + d]) << (16*c);
                *(unsigned long long*)&rembTk[d][8] = p0;
                *(unsigned long long*)&rembTk[d][12] = p1;
            }
        }
    }
    float vreg[4] = {0,0,0,0};
    float evreg[8] = {0,0,0,0,0,0,0,0};
    if (PASSB) {
        const int cv = tid >> 4, ap = (tid & 15) * 4;
        const int o = g*32 + 16 + cv;
        const float A = a1[o], Bc = b1[o];
        const ushort4 vv = *(const ushort4*)&qkvb[((size_t)n*512 + o)*64 + ap];
        vreg[0] = A*bf2f(vv.x) + Bc; vreg[1] = A*bf2f(vv.y) + Bc;
        vreg[2] = A*bf2f(vv.z) + Bc; vreg[3] = A*bf2f(vv.w) + Bc;
        const int d0 = (tid & 15) * 8;
        #pragma unroll
        for (int kk = 0; kk < 8; ++kk)
            evreg[kk] = (d0 + kk < 127) ? rel_emb[(16+cv)*127 + d0 + kk] : 0.f;
    }
    __syncthreads();

    float sqe=0.f, s2qe=0.f, ske=0.f, s2ke=0.f;
    {
        const int a0 = w*16;
        const s16x8 afr = *(const s16x8*)&qkT[a0 + lb][h*8];
        #pragma unroll
        for (int dt = 0; dt < 8; ++dt) {
            const s16x8 bq = *(const s16x8*)&rembTq[dt*16 + lb][h*8];
            const s16x8 bk = *(const s16x8*)&rembTk[dt*16 + lb][h*8];
            f32x4 zz = {0.f,0.f,0.f,0.f};
            f32x4 cq = __builtin_amdgcn_mfma_f32_16x16x32_bf16(afr, bq, zz, 0,0,0);
            f32x4 ck = __builtin_amdgcn_mfma_f32_16x16x32_bf16(afr, bk, zz, 0,0,0);
            const int d = dt*16 + lb;
            #pragma unroll
            for (int r = 0; r < 4; ++r) {
                const int a = a0 + h*4 + r;
                const int i = a + 63 - d;
                if (i >= 0 && i < 64) {
                    const float vq = cq[r], vk = ck[r];
                    qeT[i][a] = f2bf(vq);
                    keT[i][a] = f2bf(vk);
                    if (!PASSB) { sqe += vq; s2qe += vq*vq; ske += vk; s2ke += vk*vk; }
                }
            }
        }
    }
    __syncthreads();

    const int i0 = w*16;
    f32x4 acc[4];
    #pragma unroll
    for (int jt = 0; jt < 4; ++jt) { acc[jt][0]=0.f; acc[jt][1]=0.f; acc[jt][2]=0.f; acc[jt][3]=0.f; }
    #pragma unroll
    for (int kc = 0; kc < 2; ++kc) {
        const s16x8 aq = *(const s16x8*)&qeT[i0 + lb][kc*32 + h*8];
        #pragma unroll
        for (int jt = 0; jt < 4; ++jt) {
            const s16x8 bk2 = *(const s16x8*)&keT[jt*16 + lb][kc*32 + h*8];
            acc[jt] = __builtin_amdgcn_mfma_f32_16x16x32_bf16(aq, bk2, acc[jt], 0,0,0);
        }
    }

    if (!PASSB) {
        float sqk=0.f, s2qk=0.f;
        #pragma unroll
        for (int jt = 0; jt < 4; ++jt)
            #pragma unroll
            for (int r = 0; r < 4; ++r) { const float q_ = acc[jt][r]; sqk += q_; s2qk += q_*q_; }
        float vals[6] = {sqk, s2qk, sqe, s2qe, ske, s2ke};
        #pragma unroll
        for (int q = 0; q < 6; ++q) {
            float v = vals[q];
            #pragma unroll
            for (int off = 32; off; off >>= 1) v += __shfl_xor(v, off);
            if (l == 0) red[w*6 + q] = v;
        }
        __syncthreads();
        if (tid < 6) p2[(size_t)bx*6 + tid] = red[tid] + red[6+tid] + red[12+tid] + red[18+tid];
        return;
    }

    {
        int4 z4; z4.x=z4.y=z4.z=z4.w=0;
        int4* dst = (int4*)sm;
        for (int t = tid; t < 1088; t += 256) dst[t] = z4;
    }

    const float c_qk = a2[g], c_qe = a2[16+g], c_ke = a2[32+g];
    float p[4][4];
    #pragma unroll
    for (int jt = 0; jt < 4; ++jt) {
        const unsigned long long q4 = *(const unsigned long long*)&qeT[jt*16 + lb][i0 + 4*h];
        const unsigned long long k4 = *(const unsigned long long*)&keT[jt*16 + lb][i0 + 4*h];
        #pragma unroll
        for (int r = 0; r < 4; ++r) {
            p[jt][r] = c_qk*acc[jt][r]
                     + c_qe*bf2f((unsigned short)(q4 >> (16*r)))
                     + c_ke*bf2f((unsigned short)(k4 >> (16*r)));
        }
    }
    #pragma unroll
    for (int r = 0; r < 4; ++r) {
        float m = fmaxf(fmaxf(p[0][r], p[1][r]), fmaxf(p[2][r], p[3][r]));
        #pragma unroll
        for (int mk = 8; mk; mk >>= 1) m = fmaxf(m, __shfl_xor(m, mk));
        float s = 0.f;
        #pragma unroll
        for (int jt = 0; jt < 4; ++jt) { p[jt][r] = __expf(p[jt][r] - m); s += p[jt][r]; }
        #pragma unroll
        for (int mk = 8; mk; mk >>= 1) s += __shfl_xor(s, mk);
        const float inv = 1.f / s;
        #pragma unroll
        for (int jt = 0; jt < 4; ++jt) p[jt][r] *= inv;
    }
    __syncthreads();

    #pragma unroll
    for (int jt = 0; jt < 4; ++jt)
        #pragma unroll
        for (int r = 0; r < 4; ++r) {
            const int i = i0 + 4*h + r, j = jt*16 + lb;
            const unsigned short pb = f2bf(p[jt][r]);
            pT[i][j] = pb;
            PSt[i][i + 63 - j] = pb;
        }
    {
        const int cv = tid >> 4, ap = (tid & 15)*4;
        unsigned long long pk = 0;
        #pragma unroll
        for (int u = 0; u < 4; ++u) pk |= (unsigned long long)f2bf(vreg[u]) << (16*u);
        *(unsigned long long*)&vbL[cv][ap] = pk;
        const int d0 = (tid & 15)*8;
        unsigned long long e0 = 0, e1 = 0;
        #pragma unroll
        for (int u = 0; u < 4; ++u) e0 |= (unsigned long long)f2bf(evreg[u]) << (16*u);
        #pragma unroll
        for (int u = 0; u < 4; ++u) e1 |= (unsigned long long)f2bf(evreg[4+u]) << (16*u);
        *(unsigned long long*)&rembV[cv][d0]   = e0;
        *(unsigned long long*)&rembV[cv][d0+4] = e1;
    }
    __syncthreads();

    f32x4 accA = {0.f,0.f,0.f,0.f}, accE = {0.f,0.f,0.f,0.f};
    #pragma unroll
    for (int kc = 0; kc < 2; ++kc) {
        const s16x8 av = *(const s16x8*)&vbL[lb][kc*32 + h*8];
        const s16x8 bp = *(const s16x8*)&pT[i0 + lb][kc*32 + h*8];
        accA = __builtin_amdgcn_mfma_f32_16x16x32_bf16(av, bp, accA, 0,0,0);
    }
    #pragma unroll
    for (int kc = 0; kc < 4; ++kc) {
        const s16x8 ae = *(const s16x8*)&rembV[lb][kc*32 + h*8];
        const s16x8 bs = *(const s16x8*)&PSt[i0 + lb][kc*32 + h*8];
        accE = __builtin_amdgcn_mfma_f32_16x16x32_bf16(ae, bs, accE, 0,0,0);
    }
    unsigned short* aw = attnb  + ((size_t)n*16 + g)*1024;
    unsigned short* ew = attneb + ((size_t)n*16 + g)*1024;
    #pragma unroll
    for (int r = 0; r < 4; ++r) {
        aw[(4*h + r)*64 + i0 + lb] = f2bf(accA[r]);
        ew[(4*h + r)*64 + i0 + lb] = f2bf(accE[r]);
    }
}

// ---------------- Kernel 4: bn2 finalize (12 blocks x 4 waves = 48 ch) ----------------
__global__ __launch_bounds__(256) void k_bn2(const float* __restrict__ p2,
                                             const float* __restrict__ gamma2,
                                             float* __restrict__ a2)
{
    const int ch = blockIdx.x*4 + (threadIdx.x >> 6);
    const int l = threadIdx.x & 63;
    const int kind = ch >> 4, g = ch & 15;
    float s = 0.f, s2 = 0.f;
    #pragma unroll
    for (int q = 0; q < 4; ++q) {
        const int nn = q*64 + l;
        const float* p = p2 + ((size_t)nn*16 + g)*6 + 2*kind;
        s += p[0]; s2 += p[1];
    }
    #pragma unroll
    for (int off = 32; off; off >>= 1) { s += __shfl_down(s, off); s2 += __shfl_down(s2, off); }
    if (l == 0) {
        const float mean = s * (1.f/1048576.f);
        const float var  = s2 * (1.f/1048576.f) - mean*mean;
        a2[ch] = gamma2[ch] * rsqrtf(var + 1e-5f);
    }
}

// ---------------- Kernel 6: bn3 stats (bf16 attn) -> a3,b3 ----------------
__global__ __launch_bounds__(256) void k_bn3(const unsigned short* __restrict__ attnb,
                                             const unsigned short* __restrict__ attneb,
                                             const float* __restrict__ gamma,
                                             const float* __restrict__ beta,
                                             float* __restrict__ a3, float* __restrict__ b3)
{
    const int o = blockIdx.x;
    const int g = o >> 5, rem = o & 31, c = rem >> 1, sflag = rem & 1;
    const unsigned short* src = (sflag ? attneb : attnb) + (size_t)g*1024 + (size_t)c*64;
    const int tid = threadIdx.x;
    float s = 0.f, s2 = 0.f;
    for (int t = tid; t < 2048; t += 256) {
        const int n = t >> 3, i8 = (t & 7) * 8;
        const s16x8 v8 = *(const s16x8*)&src[(size_t)n*16384 + i8];
        #pragma unroll
        for (int j = 0; j < 8; ++j) {
            const float f = bf2f((unsigned short)v8[j]);
            s += f; s2 += f*f;
        }
    }
    __shared__ float rs[4], rs2[4];
    #pragma unroll
    for (int off = 32; off; off >>= 1) { s += __shfl_down(s, off); s2 += __shfl_down(s2, off); }
    if ((tid & 63) == 0) { rs[tid>>6] = s; rs2[tid>>6] = s2; }
    __syncthreads();
    if (tid == 0) {
        const float S  = rs[0]+rs[1]+rs[2]+rs[3];
        const float S2 = rs2[0]+rs2[1]+rs2[2]+rs2[3];
        const float mean = S * (1.f/16384.f);
        const float var  = S2 * (1.f/16384.f) - mean*mean;
        const float A = gamma[o] * rsqrtf(var + 1e-5f);
        a3[o] = A;
        b3[o] = beta[o] - mean*A;
    }
}

// ---------------- Kernel 7: apply bn3, sum channel pairs, transpose ----------------
__global__ __launch_bounds__(256) void k_out(const unsigned short* __restrict__ attnb,
                                             const unsigned short* __restrict__ attneb,
                                             const float* __restrict__ a3,
                                             const float* __restrict__ b3,
                                             float* __restrict__ out)
{
    const int idx = blockIdx.x*256 + threadIdx.x;
    const int i  = idx & 63;
    const int h  = (idx >> 6) & 63;
    const int oc = (idx >> 12) & 255;
    const int b  = idx >> 20;
    const int g = oc >> 4, c = oc & 15;
    const int n = b*64 + h;
    const size_t src = ((size_t)n*16 + g)*1024 + (size_t)c*64 + i;
    const int o0 = g*32 + 2*c;
    out[idx] = a3[o0]*bf2f(attnb[src]) + a3[o0+1]*bf2f(attneb[src]) + (b3[o0] + b3[o0+1]);
}

extern "C" void kernel_launch(void* const* d_in, const int* in_sizes, int n_in,
                              void* d_out, int out_size, void* d_ws, size_t ws_size,
                              hipStream_t stream) {
    const float* x    = (const float*)d_in[0];
    const float* w    = (const float*)d_in[1];
    const float* g1   = (const float*)d_in[2];
    const float* be1  = (const float*)d_in[3];
    const float* remb = (const float*)d_in[4];
    const float* g2   = (const float*)d_in[5];
    const float* g3   = (const float*)d_in[7];
    const float* be3  = (const float*)d_in[8];
    float* out = (float*)d_out;
    float* ws  = (float*)d_ws;

    unsigned short* qkvb  = (unsigned short*)(ws + OFF_QKV);
    float* a1    = ws + OFF_A1;
    float* b1    = ws + OFF_B1;
    float* p2    = ws + OFF_P2;
    float* a2    = ws + OFF_A2;
    unsigned short* attnb  = (unsigned short*)(ws + OFF_ATTN);
    unsigned short* attneb = (unsigned short*)(ws + OFF_ATTNE);
    float* a3    = ws + OFF_A3;
    float* b3    = ws + OFF_B3;
    unsigned short* xTh = (unsigned short*)(ws + OFF_XTH);
    unsigned short* wh  = (unsigned short*)(ws + OFF_WH);
    unsigned short* wl  = (unsigned short*)(ws + OFF_WL);

    const int SHM = 39040;
    k_split<<<256, 256, 0, stream>>>(x, xTh);
    k_wsplit<<<128, 256, 0, stream>>>(w, wh, wl);
    k_qkv_mfma<<<dim3(4, 128), 512, 0, stream>>>(wh, wl, xTh, qkvb);
    k_bn1<<<512, 256, 0, stream>>>(qkvb, g1, be1, a1, b1);
    k_pass2<0><<<4096, 256, SHM, stream>>>(qkvb, a1, b1, remb, p2, nullptr, nullptr, nullptr);
    k_bn2<<<12, 256, 0, stream>>>(p2, g2, a2);
    k_pass2<1><<<4096, 256, SHM, stream>>>(qkvb, a1, b1, remb, nullptr, a2, attnb, attneb);
    k_bn3<<<512, 256, 0, stream>>>(attnb, attneb, g3, be3, a3, b3);
    k_out<<<16384, 256, 0, stream>>>(attnb, attneb, a3, b3, out);
}

// Round 9
// 115.139 us; speedup vs baseline: 3.7538x; 1.0342x over previous
//
#include <hip/hip_runtime.h>
#include <hip/hip_bf16.h>

typedef short s16x8 __attribute__((ext_vector_type(8)));
typedef float f32x4 __attribute__((ext_vector_type(4)));
typedef unsigned long long u64;

static __device__ __forceinline__ unsigned short f2bf(float f){
    unsigned int u = __float_as_uint(f);
    u += 0x7fffu + ((u >> 16) & 1u);
    return (unsigned short)(u >> 16);
}
static __device__ __forceinline__ float bf2f(unsigned short h){
    return __uint_as_float(((unsigned int)h) << 16);
}

// ---------------- workspace layout (float offsets) ----------------
static const size_t OFF_QKV   = 0;         // bf16[256][512][64]
static const size_t OFF_A1    = 8388608;
static const size_t OFF_B1    = 8389120;
static const size_t OFF_P2    = 8389632;
static const size_t OFF_A2    = 8414208;
static const size_t OFF_ATTN  = 8414272;   // bf16[256][16][16][64]
static const size_t OFF_ATTNE = 12608576;  // bf16[256][16][16][64]
static const size_t OFF_A3    = 16802880;
static const size_t OFF_B3    = 16803392;
static const size_t OFF_IMGQ  = 16803904;  // u16[128][32] (rembTq LDS image)
static const size_t OFF_IMGK  = 16805952;  // u16[128][32] (contiguous with IMGQ)
static const size_t OFF_IMGV  = 16808000;  // u16[16][136]
static const size_t OFF_ZQK   = 16809088;  // u64[4096][256][4] bf16 blobs
static const size_t OFF_ZQE   = 25197696;
static const size_t OFF_ZKE   = 33586304;  // end 41,974,912 floats ~ 168 MB (ws ~252 MB per fill evidence)
// transients (dead before pass2<1> writes attn/attne):
static const size_t OFF_XTH = OFF_ATTN;               // bf16[16384][256]
static const size_t OFF_WH  = OFF_ATTN + 4194304;     // bf16[512][256]
static const size_t OFF_WL  = OFF_ATTN + 4259840;     // bf16[512][256]

// ---------------- Kernel 0a: bf16 round + transpose x -> xT [(n,i)][c] ----------------
__global__ __launch_bounds__(256) void k_split(const float* __restrict__ x,
                                               unsigned short* __restrict__ xTh)
{
    __shared__ unsigned short xs[64*264];
    const int n = blockIdx.x;
    const int b = n >> 6, h = n & 63;
    const float* xbase = x + (size_t)b*256*4096 + (size_t)h*64;
    const int tid = threadIdx.x;
    const int iw = tid >> 2, cch = (tid & 3) * 64;
    const size_t row = (size_t)n*64 + iw;
    {
        const int c = tid;
        #pragma unroll 4
        for (int ic = 0; ic < 16; ++ic) {
            const float4 v = *(const float4*)&xbase[(size_t)c*4096 + ic*4];
            const float vv[4] = {v.x, v.y, v.z, v.w};
            #pragma unroll
            for (int u = 0; u < 4; ++u) xs[(ic*4+u)*264 + c] = f2bf(vv[u]);
        }
    }
    __syncthreads();
    #pragma unroll
    for (int u8 = 0; u8 < 8; ++u8)
        *(s16x8*)&xTh[row*256 + cch + u8*8] = *(const s16x8*)&xs[iw*264 + cch + u8*8];
}

// ---------------- Kernel 0b: split w -> wh, wl bf16 ; block 128 = rel_emb image prep ----------------
__global__ __launch_bounds__(256) void k_wsplit(const float* __restrict__ w,
                                                const float* __restrict__ remb,
                                                unsigned short* __restrict__ wh,
                                                unsigned short* __restrict__ wl,
                                                u64* __restrict__ imgQ64,   // [128][8] u64 (imgQ+imgK contiguous)
                                                unsigned short* __restrict__ imgV)
{
    const int tid = threadIdx.x;
    if (blockIdx.x == 128) {
        if (tid < 128) {
            const int d = tid;
            u64 a0 = 0, a1v = 0, b2 = 0, b3 = 0;
            if (d < 127) {
                #pragma unroll
                for (int c = 0; c < 4; ++c) a0  |= (u64)f2bf(remb[c*127 + d])      << (16*c);
                #pragma unroll
                for (int c = 0; c < 4; ++c) a1v |= (u64)f2bf(remb[(4+c)*127 + d])  << (16*c);
                #pragma unroll
                for (int c = 0; c < 4; ++c) b2  |= (u64)f2bf(remb[(8+c)*127 + d])  << (16*c);
                #pragma unroll
                for (int c = 0; c < 4; ++c) b3  |= (u64)f2bf(remb[(12+c)*127 + d]) << (16*c);
            }
            u64* rowQ = imgQ64 + (size_t)d*8;
            rowQ[0] = a0; rowQ[1] = a1v; rowQ[2] = 0; rowQ[3] = 0;
            rowQ[4] = 0;  rowQ[5] = 0;   rowQ[6] = 0; rowQ[7] = 0;
            u64* rowK = imgQ64 + 1024 + (size_t)d*8;    // imgK starts 128*8 u64 later
            rowK[0] = 0;  rowK[1] = 0;   rowK[2] = b2; rowK[3] = b3;
            rowK[4] = 0;  rowK[5] = 0;   rowK[6] = 0;  rowK[7] = 0;
        } else {
            for (int e = tid - 128; e < 2176; e += 128) {
                const int cv = e / 136, dd = e - cv*136;
                imgV[e] = (dd < 127) ? f2bf(remb[(16+cv)*127 + dd]) : (unsigned short)0;
            }
        }
        return;
    }
    const int t4 = blockIdx.x*256 + tid;
    const float4 v = *(const float4*)&w[(size_t)t4*4];
    const float vv[4] = {v.x, v.y, v.z, v.w};
    ushort4 hi4, lo4;
    unsigned short* hp = (unsigned short*)&hi4;
    unsigned short* lp = (unsigned short*)&lo4;
    #pragma unroll
    for (int u = 0; u < 4; ++u) {
        hp[u] = f2bf(vv[u]);
        lp[u] = f2bf(vv[u] - bf2f(hp[u]));
    }
    *(ushort4*)&wh[(size_t)t4*4] = hi4;
    *(ushort4*)&wl[(size_t)t4*4] = lo4;
}

// ---------------- Kernel 1: qkv(bf16) = (wh+wl).xh via MFMA (verified round 8) ----------------
__global__ __launch_bounds__(512) void k_qkv_mfma(const unsigned short* __restrict__ wh,
                                                  const unsigned short* __restrict__ wl,
                                                  const unsigned short* __restrict__ xTh,
                                                  unsigned short* __restrict__ qkvb)
{
    __shared__ char smraw[34816];
    unsigned short* const Ah = (unsigned short*)smraw;           // [128][40]
    unsigned short* const Al = Ah + 5120;
    unsigned short* const Bh = Al + 5120;
    unsigned short* const Cl = (unsigned short*)smraw;           // [128][136] overlay
    const int o0   = blockIdx.x * 128;
    const int col0 = blockIdx.y * 128;
    const int tid = threadIdx.x;
    const int w = tid >> 6, l = tid & 63, lb = l & 15, h = l >> 4;
    const int oq = (w >> 2) * 64, cq = (w & 3) * 32;

    f32x4 acc[4][2];
    #pragma unroll
    for (int m = 0; m < 4; ++m)
        #pragma unroll
        for (int nn = 0; nn < 2; ++nn) { acc[m][nn][0]=0.f; acc[m][nn][1]=0.f; acc[m][nn][2]=0.f; acc[m][nn][3]=0.f; }

    const int srow = tid >> 2, sc8 = (tid & 3) * 8;
    int4 rA, rL, rB;
    rA = *(const int4*)(wh  + (size_t)(o0  +srow)*256 + sc8);
    rL = *(const int4*)(wl  + (size_t)(o0  +srow)*256 + sc8);
    rB = *(const int4*)(xTh + (size_t)(col0+srow)*256 + sc8);
    *(int4*)&Ah[srow*40 + sc8] = rA;
    *(int4*)&Al[srow*40 + sc8] = rL;
    *(int4*)&Bh[srow*40 + sc8] = rB;

    for (int step = 0; step < 8; ++step) {
        __syncthreads();
        if (step < 7) {
            const int kk = (step+1)*32;
            rA = *(const int4*)(wh  + (size_t)(o0  +srow)*256 + kk + sc8);
            rL = *(const int4*)(wl  + (size_t)(o0  +srow)*256 + kk + sc8);
            rB = *(const int4*)(xTh + (size_t)(col0+srow)*256 + kk + sc8);
        }
        s16x8 ah[4], al[4], bf[2];
        #pragma unroll
        for (int m = 0; m < 4; ++m)  ah[m] = *(const s16x8*)&Ah[(oq + m*16 + lb)*40 + h*8];
        #pragma unroll
        for (int m = 0; m < 4; ++m)  al[m] = *(const s16x8*)&Al[(oq + m*16 + lb)*40 + h*8];
        #pragma unroll
        for (int nn = 0; nn < 2; ++nn) bf[nn] = *(const s16x8*)&Bh[(cq + nn*16 + lb)*40 + h*8];
        #pragma unroll
        for (int m = 0; m < 4; ++m)
            #pragma unroll
            for (int nn = 0; nn < 2; ++nn) {
                acc[m][nn] = __builtin_amdgcn_mfma_f32_16x16x32_bf16(ah[m], bf[nn], acc[m][nn], 0,0,0);
                acc[m][nn] = __builtin_amdgcn_mfma_f32_16x16x32_bf16(al[m], bf[nn], acc[m][nn], 0,0,0);
            }
        __syncthreads();
        if (step < 7) {
            *(int4*)&Ah[srow*40 + sc8] = rA;
            *(int4*)&Al[srow*40 + sc8] = rL;
            *(int4*)&Bh[srow*40 + sc8] = rB;
        }
    }

    #pragma unroll
    for (int m = 0; m < 4; ++m)
        #pragma unroll
        for (int nn = 0; nn < 2; ++nn)
            #pragma unroll
            for (int r = 0; r < 4; ++r)
                Cl[(oq + m*16 + h*4 + r)*136 + cq + nn*16 + lb] = f2bf(acc[m][nn][r]);
    __syncthreads();
    const int erow = tid >> 2, eseg = (tid & 3) * 16;
    #pragma unroll
    for (int h2 = 0; h2 < 2; ++h2) {
        unsigned short* dst = qkvb + ((size_t)((col0 >> 6) + h2)*512 + (o0 + erow))*64 + eseg;
        *(s16x8*)&dst[0] = *(const s16x8*)&Cl[erow*136 + h2*64 + eseg];
        *(s16x8*)&dst[8] = *(const s16x8*)&Cl[erow*136 + h2*64 + eseg + 8];
    }
}

// ---------------- Kernel 2: bn1 stats (bf16 qkv) -> folded affine a1,b1 ----------------
__global__ __launch_bounds__(256) void k_bn1(const unsigned short* __restrict__ qkvb,
                                             const float* __restrict__ gamma,
                                             const float* __restrict__ beta,
                                             float* __restrict__ a1, float* __restrict__ b1)
{
    const int o = blockIdx.x;
    const int tid = threadIdx.x;
    float s = 0.f, s2 = 0.f;
    for (int t = tid; t < 2048; t += 256) {
        const int n = t >> 3, i8 = (t & 7) * 8;
        const s16x8 v8 = *(const s16x8*)&qkvb[((size_t)n*512 + o)*64 + i8];
        #pragma unroll
        for (int j = 0; j < 8; ++j) {
            const float f = bf2f((unsigned short)v8[j]);
            s += f; s2 += f*f;
        }
    }
    __shared__ float rs[4], rs2[4];
    #pragma unroll
    for (int off = 32; off; off >>= 1) { s += __shfl_down(s, off); s2 += __shfl_down(s2, off); }
    if ((tid & 63) == 0) { rs[tid>>6] = s; rs2[tid>>6] = s2; }
    __syncthreads();
    if (tid == 0) {
        const float S  = rs[0]+rs[1]+rs[2]+rs[3];
        const float S2 = rs2[0]+rs2[1]+rs2[2]+rs2[3];
        const float mean = S * (1.f/16384.f);
        const float var  = S2 * (1.f/16384.f) - mean*mean;
        const float A = gamma[o] * rsqrtf(var + 1e-5f);
        a1[o] = A;
        b1[o] = beta[o] - mean*A;
    }
}

// ---------------- Kernels 3/5: per-(n,g) core.
// passA: qe/ke/qk compute + stats + z-blob stores.  passB: blob z-combine + softmax + attn. ----------------
template<int PASSB>
__global__ __launch_bounds__(256) void k_pass2(const unsigned short* __restrict__ qkvb,
    const float* __restrict__ a1, const float* __restrict__ b1,
    const unsigned short* __restrict__ imgQK, const unsigned short* __restrict__ imgV,
    float* __restrict__ p2, const float* __restrict__ a2,
    u64* __restrict__ zqk, u64* __restrict__ zqe, u64* __restrict__ zke,
    unsigned short* __restrict__ attnb, unsigned short* __restrict__ attneb)
{
    extern __shared__ char sm[];
    unsigned short (* const qkT)[32]    = (unsigned short(*)[32])(sm);
    unsigned short (* const rembTq)[32] = (unsigned short(*)[32])(sm + 4096);
    unsigned short (* const rembTk)[32] = (unsigned short(*)[32])(sm + 12288);
    unsigned short (* const PSt)[136]   = (unsigned short(*)[136])(sm);
    unsigned short (* const qeT)[72]    = (unsigned short(*)[72])(sm + 20480);
    unsigned short (* const pT)[72]     = (unsigned short(*)[72])(sm + 20480);
    unsigned short (* const keT)[72]    = (unsigned short(*)[72])(sm + 29696);
    unsigned short (* const rembV)[136] = (unsigned short(*)[136])(sm + 29696);
    unsigned short (* const vbL)[72]    = (unsigned short(*)[72])(sm + 34048);
    float* const red = (float*)(sm + 38912);

    const int bx = blockIdx.x, n = bx >> 4, g = bx & 15;
    const int tid = threadIdx.x;
    const int w = tid >> 6, l = tid & 63, lb = l & 15, h = l >> 4;
    const int i0 = w*16;
    const size_t bbase = ((size_t)bx*256 + tid)*4;

    if (!PASSB) {
        {   // copy rembTq+rembTk images (16 KB contiguous)
            const int4* gsrc = (const int4*)imgQK;
            int4* ldst = (int4*)(sm + 4096);
            for (int t = tid; t < 1024; t += 256) ldst[t] = gsrc[t];
        }
        {   // qkT staging
            const int a = tid & 63, c0 = (tid >> 6) * 4;
            u64 pk = 0;
            #pragma unroll
            for (int u = 0; u < 4; ++u) {
                const int o = g*32 + c0 + u;
                const float val = a1[o] * bf2f(qkvb[((size_t)n*512 + o)*64 + a]) + b1[o];
                pk |= (u64)f2bf(val) << (16*u);
            }
            *(u64*)&qkT[a][c0] = pk;
            *(u64*)&qkT[a][16 + c0] = 0ull;
        }
        __syncthreads();

        // qe/ke GEMMs + skew scatter + stats
        float sqe=0.f, s2qe=0.f, ske=0.f, s2ke=0.f;
        {
            const int a0 = w*16;
            const s16x8 afr = *(const s16x8*)&qkT[a0 + lb][h*8];
            #pragma unroll
            for (int dt = 0; dt < 8; ++dt) {
                const s16x8 bq = *(const s16x8*)&rembTq[dt*16 + lb][h*8];
                const s16x8 bk = *(const s16x8*)&rembTk[dt*16 + lb][h*8];
                f32x4 zz = {0.f,0.f,0.f,0.f};
                f32x4 cqf = __builtin_amdgcn_mfma_f32_16x16x32_bf16(afr, bq, zz, 0,0,0);
                f32x4 ckf = __builtin_amdgcn_mfma_f32_16x16x32_bf16(afr, bk, zz, 0,0,0);
                const int d = dt*16 + lb;
                #pragma unroll
                for (int r = 0; r < 4; ++r) {
                    const int a = a0 + h*4 + r;
                    const int i = a + 63 - d;
                    if (i >= 0 && i < 64) {
                        const float vq = cqf[r], vk = ckf[r];
                        qeT[i][a] = f2bf(vq);
                        keT[i][a] = f2bf(vk);
                        sqe += vq; s2qe += vq*vq; ske += vk; s2ke += vk*vk;
                    }
                }
            }
        }
        __syncthreads();

        // qk GEMM
        f32x4 acc[4];
        #pragma unroll
        for (int jt = 0; jt < 4; ++jt) { acc[jt][0]=0.f; acc[jt][1]=0.f; acc[jt][2]=0.f; acc[jt][3]=0.f; }
        #pragma unroll
        for (int kc = 0; kc < 2; ++kc) {
            const s16x8 aq = *(const s16x8*)&qeT[i0 + lb][kc*32 + h*8];
            #pragma unroll
            for (int jt = 0; jt < 4; ++jt) {
                const s16x8 bk2 = *(const s16x8*)&keT[jt*16 + lb][kc*32 + h*8];
                acc[jt] = __builtin_amdgcn_mfma_f32_16x16x32_bf16(aq, bk2, acc[jt], 0,0,0);
            }
        }

        // z-blob stores (bf16, thread-contiguous) + qk stats
        float sqk=0.f, s2qk=0.f;
        #pragma unroll
        for (int jt = 0; jt < 4; ++jt) {
            const u64 q4 = *(const u64*)&qeT[jt*16 + lb][i0 + 4*h];
            const u64 k4 = *(const u64*)&keT[jt*16 + lb][i0 + 4*h];
            zqe[bbase + jt] = q4;
            zke[bbase + jt] = k4;
            u64 pk = 0;
            #pragma unroll
            for (int r = 0; r < 4; ++r) {
                const float q_ = acc[jt][r];
                sqk += q_; s2qk += q_*q_;
                pk |= (u64)f2bf(q_) << (16*r);
            }
            zqk[bbase + jt] = pk;
        }

        float vals[6] = {sqk, s2qk, sqe, s2qe, ske, s2ke};
        #pragma unroll
        for (int q = 0; q < 6; ++q) {
            float v = vals[q];
            #pragma unroll
            for (int off = 32; off; off >>= 1) v += __shfl_xor(v, off);
            if (l == 0) red[w*6 + q] = v;
        }
        __syncthreads();
        if (tid < 6) p2[(size_t)bx*6 + tid] = red[tid] + red[6+tid] + red[12+tid] + red[18+tid];
        return;
    }

    // ================= PASS B =================
    {   // zero PSt
        int4 z4i; z4i.x=z4i.y=z4i.z=z4i.w=0;
        int4* dst = (int4*)sm;
        for (int t = tid; t < 1088; t += 256) dst[t] = z4i;
    }
    {   // copy rembV image
        const int4* gsrc = (const int4*)imgV;
        int4* ldst = (int4*)(sm + 29696);
        for (int t = tid; t < 272; t += 256) ldst[t] = gsrc[t];
    }
    {   // V staging direct to vbL
        const int cv = tid >> 4, ap = (tid & 15) * 4;
        const int o = g*32 + 16 + cv;
        const float A = a1[o], Bc = b1[o];
        const ushort4 vv = *(const ushort4*)&qkvb[((size_t)n*512 + o)*64 + ap];
        u64 pk = 0;
        pk |= (u64)f2bf(A*bf2f(vv.x) + Bc);
        pk |= (u64)f2bf(A*bf2f(vv.y) + Bc) << 16;
        pk |= (u64)f2bf(A*bf2f(vv.z) + Bc) << 32;
        pk |= (u64)f2bf(A*bf2f(vv.w) + Bc) << 48;
        *(u64*)&vbL[cv][ap] = pk;
    }

    // blob loads + z-combine + in-register softmax
    const float c_qk = a2[g], c_qe = a2[16+g], c_ke = a2[32+g];
    float p[4][4];
    #pragma unroll
    for (int jt = 0; jt < 4; ++jt) {
        const u64 zq = zqk[bbase + jt];
        const u64 q4 = zqe[bbase + jt];
        const u64 k4 = zke[bbase + jt];
        #pragma unroll
        for (int r = 0; r < 4; ++r) {
            p[jt][r] = c_qk*bf2f((unsigned short)(zq >> (16*r)))
                     + c_qe*bf2f((unsigned short)(q4 >> (16*r)))
                     + c_ke*bf2f((unsigned short)(k4 >> (16*r)));
        }
    }
    #pragma unroll
    for (int r = 0; r < 4; ++r) {
        float m = fmaxf(fmaxf(p[0][r], p[1][r]), fmaxf(p[2][r], p[3][r]));
        #pragma unroll
        for (int mk = 8; mk; mk >>= 1) m = fmaxf(m, __shfl_xor(m, mk));
        float s = 0.f;
        #pragma unroll
        for (int jt = 0; jt < 4; ++jt) { p[jt][r] = __expf(p[jt][r] - m); s += p[jt][r]; }
        #pragma unroll
        for (int mk = 8; mk; mk >>= 1) s += __shfl_xor(s, mk);
        const float inv = 1.f / s;
        #pragma unroll
        for (int jt = 0; jt < 4; ++jt) p[jt][r] *= inv;
    }
    __syncthreads();   // PSt zero + vbL/rembV staged before scatter/use

    #pragma unroll
    for (int jt = 0; jt < 4; ++jt)
        #pragma unroll
        for (int r = 0; r < 4; ++r) {
            const int i = i0 + 4*h + r, j = jt*16 + lb;
            const unsigned short pb = f2bf(p[jt][r]);
            pT[i][j] = pb;
            PSt[i][i + 63 - j] = pb;
        }
    __syncthreads();

    f32x4 accA = {0.f,0.f,0.f,0.f}, accE = {0.f,0.f,0.f,0.f};
    #pragma unroll
    for (int kc = 0; kc < 2; ++kc) {
        const s16x8 av = *(const s16x8*)&vbL[lb][kc*32 + h*8];
        const s16x8 bp = *(const s16x8*)&pT[i0 + lb][kc*32 + h*8];
        accA = __builtin_amdgcn_mfma_f32_16x16x32_bf16(av, bp, accA, 0,0,0);
    }
    #pragma unroll
    for (int kc = 0; kc < 4; ++kc) {
        const s16x8 ae = *(const s16x8*)&rembV[lb][kc*32 + h*8];
        const s16x8 bs = *(const s16x8*)&PSt[i0 + lb][kc*32 + h*8];
        accE = __builtin_amdgcn_mfma_f32_16x16x32_bf16(ae, bs, accE, 0,0,0);
    }
    unsigned short* aw = attnb  + ((size_t)n*16 + g)*1024;
    unsigned short* ew = attneb + ((size_t)n*16 + g)*1024;
    #pragma unroll
    for (int r = 0; r < 4; ++r) {
        aw[(4*h + r)*64 + i0 + lb] = f2bf(accA[r]);
        ew[(4*h + r)*64 + i0 + lb] = f2bf(accE[r]);
    }
}

// ---------------- Kernel 4: bn2 finalize ----------------
__global__ __launch_bounds__(256) void k_bn2(const float* __restrict__ p2,
                                             const float* __restrict__ gamma2,
                                             float* __restrict__ a2)
{
    const int ch = blockIdx.x*4 + (threadIdx.x >> 6);
    const int l = threadIdx.x & 63;
    const int kind = ch >> 4, g = ch & 15;
    float s = 0.f, s2 = 0.f;
    #pragma unroll
    for (int q = 0; q < 4; ++q) {
        const int nn = q*64 + l;
        const float* p = p2 + ((size_t)nn*16 + g)*6 + 2*kind;
        s += p[0]; s2 += p[1];
    }
    #pragma unroll
    for (int off = 32; off; off >>= 1) { s += __shfl_down(s, off); s2 += __shfl_down(s2, off); }
    if (l == 0) {
        const float mean = s * (1.f/1048576.f);
        const float var  = s2 * (1.f/1048576.f) - mean*mean;
        a2[ch] = gamma2[ch] * rsqrtf(var + 1e-5f);
    }
}

// ---------------- Kernel 6: bn3 stats (bf16 attn) -> a3,b3 ----------------
__global__ __launch_bounds__(256) void k_bn3(const unsigned short* __restrict__ attnb,
                                             const unsigned short* __restrict__ attneb,
                                             const float* __restrict__ gamma,
                                             const float* __restrict__ beta,
                                             float* __restrict__ a3, float* __restrict__ b3)
{
    const int o = blockIdx.x;
    const int g = o >> 5, rem = o & 31, c = rem >> 1, sflag = rem & 1;
    const unsigned short* src = (sflag ? attneb : attnb) + (size_t)g*1024 + (size_t)c*64;
    const int tid = threadIdx.x;
    float s = 0.f, s2 = 0.f;
    for (int t = tid; t < 2048; t += 256) {
        const int n = t >> 3, i8 = (t & 7) * 8;
        const s16x8 v8 = *(const s16x8*)&src[(size_t)n*16384 + i8];
        #pragma unroll
        for (int j = 0; j < 8; ++j) {
            const float f = bf2f((unsigned short)v8[j]);
            s += f; s2 += f*f;
        }
    }
    __shared__ float rs[4], rs2[4];
    #pragma unroll
    for (int off = 32; off; off >>= 1) { s += __shfl_down(s, off); s2 += __shfl_down(s2, off); }
    if ((tid & 63) == 0) { rs[tid>>6] = s; rs2[tid>>6] = s2; }
    __syncthreads();
    if (tid == 0) {
        const float S  = rs[0]+rs[1]+rs[2]+rs[3];
        const float S2 = rs2[0]+rs2[1]+rs2[2]+rs2[3];
        const float mean = S * (1.f/16384.f);
        const float var  = S2 * (1.f/16384.f) - mean*mean;
        const float A = gamma[o] * rsqrtf(var + 1e-5f);
        a3[o] = A;
        b3[o] = beta[o] - mean*A;
    }
}

// ---------------- Kernel 7: apply bn3, sum channel pairs, transpose ----------------
__global__ __launch_bounds__(256) void k_out(const unsigned short* __restrict__ attnb,
                                             const unsigned short* __restrict__ attneb,
                                             const float* __restrict__ a3,
                                             const float* __restrict__ b3,
                                             float* __restrict__ out)
{
    const int idx = blockIdx.x*256 + threadIdx.x;
    const int i  = idx & 63;
    const int h  = (idx >> 6) & 63;
    const int oc = (idx >> 12) & 255;
    const int b  = idx >> 20;
    const int g = oc >> 4, c = oc & 15;
    const int n = b*64 + h;
    const size_t src = ((size_t)n*16 + g)*1024 + (size_t)c*64 + i;
    const int o0 = g*32 + 2*c;
    out[idx] = a3[o0]*bf2f(attnb[src]) + a3[o0+1]*bf2f(attneb[src]) + (b3[o0] + b3[o0+1]);
}

extern "C" void kernel_launch(void* const* d_in, const int* in_sizes, int n_in,
                              void* d_out, int out_size, void* d_ws, size_t ws_size,
                              hipStream_t stream) {
    const float* x    = (const float*)d_in[0];
    const float* w    = (const float*)d_in[1];
    const float* g1   = (const float*)d_in[2];
    const float* be1  = (const float*)d_in[3];
    const float* remb = (const float*)d_in[4];
    const float* g2   = (const float*)d_in[5];
    const float* g3   = (const float*)d_in[7];
    const float* be3  = (const float*)d_in[8];
    float* out = (float*)d_out;
    float* ws  = (float*)d_ws;

    unsigned short* qkvb  = (unsigned short*)(ws + OFF_QKV);
    float* a1    = ws + OFF_A1;
    float* b1    = ws + OFF_B1;
    float* p2    = ws + OFF_P2;
    float* a2    = ws + OFF_A2;
    unsigned short* attnb  = (unsigned short*)(ws + OFF_ATTN);
    unsigned short* attneb = (unsigned short*)(ws + OFF_ATTNE);
    float* a3    = ws + OFF_A3;
    float* b3    = ws + OFF_B3;
    unsigned short* imgQK = (unsigned short*)(ws + OFF_IMGQ);
    unsigned short* imgV  = (unsigned short*)(ws + OFF_IMGV);
    u64* zqk = (u64*)(ws + OFF_ZQK);
    u64* zqe = (u64*)(ws + OFF_ZQE);
    u64* zke = (u64*)(ws + OFF_ZKE);
    unsigned short* xTh = (unsigned short*)(ws + OFF_XTH);
    unsigned short* wh  = (unsigned short*)(ws + OFF_WH);
    unsigned short* wl  = (unsigned short*)(ws + OFF_WL);

    const int SHM = 39040;
    k_split<<<256, 256, 0, stream>>>(x, xTh);
    k_wsplit<<<129, 256, 0, stream>>>(w, remb, wh, wl, (u64*)imgQK, imgV);
    k_qkv_mfma<<<dim3(4, 128), 512, 0, stream>>>(wh, wl, xTh, qkvb);
    k_bn1<<<512, 256, 0, stream>>>(qkvb, g1, be1, a1, b1);
    k_pass2<0><<<4096, 256, SHM, stream>>>(qkvb, a1, b1, imgQK, imgV, p2, nullptr, zqk, zqe, zke, nullptr, nullptr);
    k_bn2<<<12, 256, 0, stream>>>(p2, g2, a2);
    k_pass2<1><<<4096, 256, SHM, stream>>>(qkvb, a1, b1, imgQK, imgV, nullptr, a2, zqk, zqe, zke, attnb, attneb);
    k_bn3<<<512, 256, 0, stream>>>(attnb, attneb, g3, be3, a3, b3);
    k_out<<<16384, 256, 0, stream>>>(attnb, attneb, a3, b3, out);
}

// Round 10
// 110.432 us; speedup vs baseline: 3.9139x; 1.0426x over previous
//
#include <hip/hip_runtime.h>
#include <hip/hip_bf16.h>

typedef short s16x8 __attribute__((ext_vector_type(8)));
typedef float f32x4 __attribute__((ext_vector_type(4)));
typedef unsigned long long u64;

static __device__ __forceinline__ unsigned short f2bf(float f){
    unsigned int u = __float_as_uint(f);
    u += 0x7fffu + ((u >> 16) & 1u);
    return (unsigned short)(u >> 16);
}
static __device__ __forceinline__ float bf2f(unsigned short h){
    return __uint_as_float(((unsigned int)h) << 16);
}

// ---------------- workspace layout (float offsets) ----------------
static const size_t OFF_QKV   = 0;         // bf16[256][512][64]
static const size_t OFF_A1    = 8388608;
static const size_t OFF_B1    = 8389120;
static const size_t OFF_P2    = 8389632;
static const size_t OFF_A2    = 8414208;
static const size_t OFF_ATTN  = 8414272;   // bf16[256][16][16][64]
static const size_t OFF_ATTNE = 12608576;  // bf16[256][16][16][64]
static const size_t OFF_A3    = 16802880;
static const size_t OFF_B3    = 16803392;
static const size_t OFF_IMGQ  = 16803904;  // u16[128][24] combined remb_q/remb_k image (6144 B)
static const size_t OFF_IMGV  = 16805440;  // u16[16][136]
static const size_t OFF_ZQK   = 16806528;  // u64[4096][256][4] bf16 blobs
static const size_t OFF_ZQE   = 25195136;
static const size_t OFF_ZKE   = 33583744;
// transients (dead before pass2<1> writes attn/attne):
static const size_t OFF_XTH = OFF_ATTN;               // bf16[16384][256]
static const size_t OFF_WH  = OFF_ATTN + 4194304;     // bf16[512][256]
static const size_t OFF_WL  = OFF_ATTN + 4259840;     // bf16[512][256]

// ---------------- Kernel 0a: bf16 round + transpose x -> xT [(n,i)][c] ----------------
__global__ __launch_bounds__(256) void k_split(const float* __restrict__ x,
                                               unsigned short* __restrict__ xTh)
{
    __shared__ unsigned short xs[64*264];
    const int n = blockIdx.x;
    const int b = n >> 6, h = n & 63;
    const float* xbase = x + (size_t)b*256*4096 + (size_t)h*64;
    const int tid = threadIdx.x;
    const int iw = tid >> 2, cch = (tid & 3) * 64;
    const size_t row = (size_t)n*64 + iw;
    {
        const int c = tid;
        #pragma unroll 4
        for (int ic = 0; ic < 16; ++ic) {
            const float4 v = *(const float4*)&xbase[(size_t)c*4096 + ic*4];
            const float vv[4] = {v.x, v.y, v.z, v.w};
            #pragma unroll
            for (int u = 0; u < 4; ++u) xs[(ic*4+u)*264 + c] = f2bf(vv[u]);
        }
    }
    __syncthreads();
    #pragma unroll
    for (int u8 = 0; u8 < 8; ++u8)
        *(s16x8*)&xTh[row*256 + cch + u8*8] = *(const s16x8*)&xs[iw*264 + cch + u8*8];
}

// ---------------- Kernel 0b: split w -> wh, wl ; block 128 = rel_emb image prep ----------------
__global__ __launch_bounds__(256) void k_wsplit(const float* __restrict__ w,
                                                const float* __restrict__ remb,
                                                unsigned short* __restrict__ wh,
                                                unsigned short* __restrict__ wl,
                                                unsigned short* __restrict__ imgQK,  // [128][24]
                                                unsigned short* __restrict__ imgV)   // [16][136]
{
    const int tid = threadIdx.x;
    if (blockIdx.x == 128) {
        if (tid < 128) {
            const int d = tid;
            u64 q0 = 0, q1 = 0, k0 = 0, k1 = 0;
            if (d < 127) {
                #pragma unroll
                for (int c = 0; c < 4; ++c) q0 |= (u64)f2bf(remb[c*127 + d])      << (16*c);
                #pragma unroll
                for (int c = 0; c < 4; ++c) q1 |= (u64)f2bf(remb[(4+c)*127 + d])  << (16*c);
                #pragma unroll
                for (int c = 0; c < 4; ++c) k0 |= (u64)f2bf(remb[(8+c)*127 + d])  << (16*c);
                #pragma unroll
                for (int c = 0; c < 4; ++c) k1 |= (u64)f2bf(remb[(12+c)*127 + d]) << (16*c);
            }
            u64* row = (u64*)(imgQK + (size_t)d*24);
            row[0] = q0; row[1] = q1; row[2] = k0; row[3] = k1; row[4] = 0; row[5] = 0;
        } else {
            for (int e = tid - 128; e < 2176; e += 128) {
                const int cv = e / 136, dd = e - cv*136;
                imgV[e] = (dd < 127) ? f2bf(remb[(16+cv)*127 + dd]) : (unsigned short)0;
            }
        }
        return;
    }
    const int t4 = blockIdx.x*256 + tid;
    const float4 v = *(const float4*)&w[(size_t)t4*4];
    const float vv[4] = {v.x, v.y, v.z, v.w};
    ushort4 hi4, lo4;
    unsigned short* hp = (unsigned short*)&hi4;
    unsigned short* lp = (unsigned short*)&lo4;
    #pragma unroll
    for (int u = 0; u < 4; ++u) {
        hp[u] = f2bf(vv[u]);
        lp[u] = f2bf(vv[u] - bf2f(hp[u]));
    }
    *(ushort4*)&wh[(size_t)t4*4] = hi4;
    *(ushort4*)&wl[(size_t)t4*4] = lo4;
}

// ---------------- Kernel 1: qkv(bf16) = (wh+wl).xh via MFMA (verified round 8) ----------------
__global__ __launch_bounds__(512) void k_qkv_mfma(const unsigned short* __restrict__ wh,
                                                  const unsigned short* __restrict__ wl,
                                                  const unsigned short* __restrict__ xTh,
                                                  unsigned short* __restrict__ qkvb)
{
    __shared__ char smraw[34816];
    unsigned short* const Ah = (unsigned short*)smraw;           // [128][40]
    unsigned short* const Al = Ah + 5120;
    unsigned short* const Bh = Al + 5120;
    unsigned short* const Cl = (unsigned short*)smraw;           // [128][136] overlay
    const int o0   = blockIdx.x * 128;
    const int col0 = blockIdx.y * 128;
    const int tid = threadIdx.x;
    const int w = tid >> 6, l = tid & 63, lb = l & 15, h = l >> 4;
    const int oq = (w >> 2) * 64, cq = (w & 3) * 32;

    f32x4 acc[4][2];
    #pragma unroll
    for (int m = 0; m < 4; ++m)
        #pragma unroll
        for (int nn = 0; nn < 2; ++nn) { acc[m][nn][0]=0.f; acc[m][nn][1]=0.f; acc[m][nn][2]=0.f; acc[m][nn][3]=0.f; }

    const int srow = tid >> 2, sc8 = (tid & 3) * 8;
    int4 rA, rL, rB;
    rA = *(const int4*)(wh  + (size_t)(o0  +srow)*256 + sc8);
    rL = *(const int4*)(wl  + (size_t)(o0  +srow)*256 + sc8);
    rB = *(const int4*)(xTh + (size_t)(col0+srow)*256 + sc8);
    *(int4*)&Ah[srow*40 + sc8] = rA;
    *(int4*)&Al[srow*40 + sc8] = rL;
    *(int4*)&Bh[srow*40 + sc8] = rB;

    for (int step = 0; step < 8; ++step) {
        __syncthreads();
        if (step < 7) {
            const int kk = (step+1)*32;
            rA = *(const int4*)(wh  + (size_t)(o0  +srow)*256 + kk + sc8);
            rL = *(const int4*)(wl  + (size_t)(o0  +srow)*256 + kk + sc8);
            rB = *(const int4*)(xTh + (size_t)(col0+srow)*256 + kk + sc8);
        }
        s16x8 ah[4], al[4], bf[2];
        #pragma unroll
        for (int m = 0; m < 4; ++m)  ah[m] = *(const s16x8*)&Ah[(oq + m*16 + lb)*40 + h*8];
        #pragma unroll
        for (int m = 0; m < 4; ++m)  al[m] = *(const s16x8*)&Al[(oq + m*16 + lb)*40 + h*8];
        #pragma unroll
        for (int nn = 0; nn < 2; ++nn) bf[nn] = *(const s16x8*)&Bh[(cq + nn*16 + lb)*40 + h*8];
        #pragma unroll
        for (int m = 0; m < 4; ++m)
            #pragma unroll
            for (int nn = 0; nn < 2; ++nn) {
                acc[m][nn] = __builtin_amdgcn_mfma_f32_16x16x32_bf16(ah[m], bf[nn], acc[m][nn], 0,0,0);
                acc[m][nn] = __builtin_amdgcn_mfma_f32_16x16x32_bf16(al[m], bf[nn], acc[m][nn], 0,0,0);
            }
        __syncthreads();
        if (step < 7) {
            *(int4*)&Ah[srow*40 + sc8] = rA;
            *(int4*)&Al[srow*40 + sc8] = rL;
            *(int4*)&Bh[srow*40 + sc8] = rB;
        }
    }

    #pragma unroll
    for (int m = 0; m < 4; ++m)
        #pragma unroll
        for (int nn = 0; nn < 2; ++nn)
            #pragma unroll
            for (int r = 0; r < 4; ++r)
                Cl[(oq + m*16 + h*4 + r)*136 + cq + nn*16 + lb] = f2bf(acc[m][nn][r]);
    __syncthreads();
    const int erow = tid >> 2, eseg = (tid & 3) * 16;
    #pragma unroll
    for (int h2 = 0; h2 < 2; ++h2) {
        unsigned short* dst = qkvb + ((size_t)((col0 >> 6) + h2)*512 + (o0 + erow))*64 + eseg;
        *(s16x8*)&dst[0] = *(const s16x8*)&Cl[erow*136 + h2*64 + eseg];
        *(s16x8*)&dst[8] = *(const s16x8*)&Cl[erow*136 + h2*64 + eseg + 8];
    }
}

// ---------------- Kernel 2: bn1 stats (bf16 qkv) -> folded affine a1,b1 ----------------
__global__ __launch_bounds__(256) void k_bn1(const unsigned short* __restrict__ qkvb,
                                             const float* __restrict__ gamma,
                                             const float* __restrict__ beta,
                                             float* __restrict__ a1, float* __restrict__ b1)
{
    const int o = blockIdx.x;
    const int tid = threadIdx.x;
    float s = 0.f, s2 = 0.f;
    for (int t = tid; t < 2048; t += 256) {
        const int n = t >> 3, i8 = (t & 7) * 8;
        const s16x8 v8 = *(const s16x8*)&qkvb[((size_t)n*512 + o)*64 + i8];
        #pragma unroll
        for (int j = 0; j < 8; ++j) {
            const float f = bf2f((unsigned short)v8[j]);
            s += f; s2 += f*f;
        }
    }
    __shared__ float rs[4], rs2[4];
    #pragma unroll
    for (int off = 32; off; off >>= 1) { s += __shfl_down(s, off); s2 += __shfl_down(s2, off); }
    if ((tid & 63) == 0) { rs[tid>>6] = s; rs2[tid>>6] = s2; }
    __syncthreads();
    if (tid == 0) {
        const float S  = rs[0]+rs[1]+rs[2]+rs[3];
        const float S2 = rs2[0]+rs2[1]+rs2[2]+rs2[3];
        const float mean = S * (1.f/16384.f);
        const float var  = S2 * (1.f/16384.f) - mean*mean;
        const float A = gamma[o] * rsqrtf(var + 1e-5f);
        a1[o] = A;
        b1[o] = beta[o] - mean*A;
    }
}

// ---------------- Kernels 3/5: per-(n,g) core.
// passA (SHM 26720): qkT[64][16]@0, rembQK[128][24]@2048, qeT[64][72]@8192,
//                    keT[64][72]@17408, red@26624. Zero K-slots via h-select fragments.
// passB (SHM 33280): PSt[64][136]@0, pT[64][72]@17408, rembV[16][136]@26624, vbL[16][72]@30976.
template<int PASSB>
__global__ __launch_bounds__(256) void k_pass2(const unsigned short* __restrict__ qkvb,
    const float* __restrict__ a1, const float* __restrict__ b1,
    const unsigned short* __restrict__ imgQK, const unsigned short* __restrict__ imgV,
    float* __restrict__ p2, const float* __restrict__ a2,
    u64* __restrict__ zqk, u64* __restrict__ zqe, u64* __restrict__ zke,
    unsigned short* __restrict__ attnb, unsigned short* __restrict__ attneb)
{
    extern __shared__ char sm[];
    const int bx = blockIdx.x, n = bx >> 4, g = bx & 15;
    const int tid = threadIdx.x;
    const int w = tid >> 6, l = tid & 63, lb = l & 15, h = l >> 4;
    const int i0 = w*16;
    const size_t bbase = ((size_t)bx*256 + tid)*4;
    const s16x8 z8 = {0,0,0,0,0,0,0,0};

    if (!PASSB) {
        unsigned short* const qkT    = (unsigned short*)sm;            // [64][16]
        unsigned short* const rembQK = (unsigned short*)(sm + 2048);   // [128][24]
        unsigned short (* const qeT)[72] = (unsigned short(*)[72])(sm + 8192);
        unsigned short (* const keT)[72] = (unsigned short(*)[72])(sm + 17408);
        float* const red = (float*)(sm + 26624);

        {   // copy rembQK image (6144 B)
            const int4* gsrc = (const int4*)imgQK;
            int4* ldst = (int4*)rembQK;
            for (int t = tid; t < 384; t += 256) ldst[t] = gsrc[t];
        }
        {   // qkT staging: cols 0..7 q, 8..15 k
            const int a = tid & 63, c0 = (tid >> 6) * 4;
            u64 pk = 0;
            #pragma unroll
            for (int u = 0; u < 4; ++u) {
                const int o = g*32 + c0 + u;
                const float val = a1[o] * bf2f(qkvb[((size_t)n*512 + o)*64 + a]) + b1[o];
                pk |= (u64)f2bf(val) << (16*u);
            }
            *(u64*)&qkT[a*16 + c0] = pk;
        }
        __syncthreads();

        // qe/ke GEMMs + skew scatter + stats
        float sqe=0.f, s2qe=0.f, ske=0.f, s2ke=0.f;
        {
            const int a0 = w*16;
            const s16x8 afr = (h < 2) ? *(const s16x8*)&qkT[(a0 + lb)*16 + h*8] : z8;
            #pragma unroll
            for (int dt = 0; dt < 8; ++dt) {
                const int dd = dt*16 + lb;
                const s16x8 bq = (h == 0) ? *(const s16x8*)&rembQK[dd*24 + 0] : z8;
                const s16x8 bk = (h == 1) ? *(const s16x8*)&rembQK[dd*24 + 8] : z8;
                f32x4 zz = {0.f,0.f,0.f,0.f};
                f32x4 cqf = __builtin_amdgcn_mfma_f32_16x16x32_bf16(afr, bq, zz, 0,0,0);
                f32x4 ckf = __builtin_amdgcn_mfma_f32_16x16x32_bf16(afr, bk, zz, 0,0,0);
                #pragma unroll
                for (int r = 0; r < 4; ++r) {
                    const int a = a0 + h*4 + r;
                    const int i = a + 63 - dd;
                    if (i >= 0 && i < 64) {
                        const float vq = cqf[r], vk = ckf[r];
                        qeT[i][a] = f2bf(vq);
                        keT[i][a] = f2bf(vk);
                        sqe += vq; s2qe += vq*vq; ske += vk; s2ke += vk*vk;
                    }
                }
            }
        }
        __syncthreads();

        // qk GEMM
        f32x4 acc[4];
        #pragma unroll
        for (int jt = 0; jt < 4; ++jt) { acc[jt][0]=0.f; acc[jt][1]=0.f; acc[jt][2]=0.f; acc[jt][3]=0.f; }
        #pragma unroll
        for (int kc = 0; kc < 2; ++kc) {
            const s16x8 aq = *(const s16x8*)&qeT[i0 + lb][kc*32 + h*8];
            #pragma unroll
            for (int jt = 0; jt < 4; ++jt) {
                const s16x8 bk2 = *(const s16x8*)&keT[jt*16 + lb][kc*32 + h*8];
                acc[jt] = __builtin_amdgcn_mfma_f32_16x16x32_bf16(aq, bk2, acc[jt], 0,0,0);
            }
        }

        // z-blob stores + qk stats
        float sqk=0.f, s2qk=0.f;
        #pragma unroll
        for (int jt = 0; jt < 4; ++jt) {
            const u64 q4 = *(const u64*)&qeT[jt*16 + lb][i0 + 4*h];
            const u64 k4 = *(const u64*)&keT[jt*16 + lb][i0 + 4*h];
            zqe[bbase + jt] = q4;
            zke[bbase + jt] = k4;
            u64 pk = 0;
            #pragma unroll
            for (int r = 0; r < 4; ++r) {
                const float q_ = acc[jt][r];
                sqk += q_; s2qk += q_*q_;
                pk |= (u64)f2bf(q_) << (16*r);
            }
            zqk[bbase + jt] = pk;
        }

        float vals[6] = {sqk, s2qk, sqe, s2qe, ske, s2ke};
        #pragma unroll
        for (int q = 0; q < 6; ++q) {
            float v = vals[q];
            #pragma unroll
            for (int off = 32; off; off >>= 1) v += __shfl_xor(v, off);
            if (l == 0) red[w*6 + q] = v;
        }
        __syncthreads();
        if (tid < 6) p2[(size_t)bx*6 + tid] = red[tid] + red[6+tid] + red[12+tid] + red[18+tid];
        return;
    }

    // ================= PASS B =================
    unsigned short (* const PSt)[136]   = (unsigned short(*)[136])(sm);
    unsigned short (* const pT)[72]     = (unsigned short(*)[72])(sm + 17408);
    unsigned short (* const rembV)[136] = (unsigned short(*)[136])(sm + 26624);
    unsigned short (* const vbL)[72]    = (unsigned short(*)[72])(sm + 30976);

    {   // zero PSt
        int4 z4i; z4i.x=z4i.y=z4i.z=z4i.w=0;
        int4* dst = (int4*)sm;
        for (int t = tid; t < 1088; t += 256) dst[t] = z4i;
    }
    {   // copy rembV image
        const int4* gsrc = (const int4*)imgV;
        int4* ldst = (int4*)rembV;
        for (int t = tid; t < 272; t += 256) ldst[t] = gsrc[t];
    }
    {   // V staging direct to vbL
        const int cv = tid >> 4, ap = (tid & 15) * 4;
        const int o = g*32 + 16 + cv;
        const float A = a1[o], Bc = b1[o];
        const ushort4 vv = *(const ushort4*)&qkvb[((size_t)n*512 + o)*64 + ap];
        u64 pk = 0;
        pk |= (u64)f2bf(A*bf2f(vv.x) + Bc);
        pk |= (u64)f2bf(A*bf2f(vv.y) + Bc) << 16;
        pk |= (u64)f2bf(A*bf2f(vv.z) + Bc) << 32;
        pk |= (u64)f2bf(A*bf2f(vv.w) + Bc) << 48;
        *(u64*)&vbL[cv][ap] = pk;
    }

    // blob loads + z-combine + in-register softmax
    const float c_qk = a2[g], c_qe = a2[16+g], c_ke = a2[32+g];
    float p[4][4];
    #pragma unroll
    for (int jt = 0; jt < 4; ++jt) {
        const u64 zq = zqk[bbase + jt];
        const u64 q4 = zqe[bbase + jt];
        const u64 k4 = zke[bbase + jt];
        #pragma unroll
        for (int r = 0; r < 4; ++r) {
            p[jt][r] = c_qk*bf2f((unsigned short)(zq >> (16*r)))
                     + c_qe*bf2f((unsigned short)(q4 >> (16*r)))
                     + c_ke*bf2f((unsigned short)(k4 >> (16*r)));
        }
    }
    #pragma unroll
    for (int r = 0; r < 4; ++r) {
        float m = fmaxf(fmaxf(p[0][r], p[1][r]), fmaxf(p[2][r], p[3][r]));
        #pragma unroll
        for (int mk = 8; mk; mk >>= 1) m = fmaxf(m, __shfl_xor(m, mk));
        float s = 0.f;
        #pragma unroll
        for (int jt = 0; jt < 4; ++jt) { p[jt][r] = __expf(p[jt][r] - m); s += p[jt][r]; }
        #pragma unroll
        for (int mk = 8; mk; mk >>= 1) s += __shfl_xor(s, mk);
        const float inv = 1.f / s;
        #pragma unroll
        for (int jt = 0; jt < 4; ++jt) p[jt][r] *= inv;
    }
    __syncthreads();

    #pragma unroll
    for (int jt = 0; jt < 4; ++jt)
        #pragma unroll
        for (int r = 0; r < 4; ++r) {
            const int i = i0 + 4*h + r, j = jt*16 + lb;
            const unsigned short pb = f2bf(p[jt][r]);
            pT[i][j] = pb;
            PSt[i][i + 63 - j] = pb;
        }
    __syncthreads();

    f32x4 accA = {0.f,0.f,0.f,0.f}, accE = {0.f,0.f,0.f,0.f};
    #pragma unroll
    for (int kc = 0; kc < 2; ++kc) {
        const s16x8 av = *(const s16x8*)&vbL[lb][kc*32 + h*8];
        const s16x8 bp = *(const s16x8*)&pT[i0 + lb][kc*32 + h*8];
        accA = __builtin_amdgcn_mfma_f32_16x16x32_bf16(av, bp, accA, 0,0,0);
    }
    #pragma unroll
    for (int kc = 0; kc < 4; ++kc) {
        const s16x8 ae = *(const s16x8*)&rembV[lb][kc*32 + h*8];
        const s16x8 bs = *(const s16x8*)&PSt[i0 + lb][kc*32 + h*8];
        accE = __builtin_amdgcn_mfma_f32_16x16x32_bf16(ae, bs, accE, 0,0,0);
    }
    unsigned short* aw = attnb  + ((size_t)n*16 + g)*1024;
    unsigned short* ew = attneb + ((size_t)n*16 + g)*1024;
    #pragma unroll
    for (int r = 0; r < 4; ++r) {
        aw[(4*h + r)*64 + i0 + lb] = f2bf(accA[r]);
        ew[(4*h + r)*64 + i0 + lb] = f2bf(accE[r]);
    }
}

// ---------------- Kernel 4: bn2 finalize ----------------
__global__ __launch_bounds__(256) void k_bn2(const float* __restrict__ p2,
                                             const float* __restrict__ gamma2,
                                             float* __restrict__ a2)
{
    const int ch = blockIdx.x*4 + (threadIdx.x >> 6);
    const int l = threadIdx.x & 63;
    const int kind = ch >> 4, g = ch & 15;
    float s = 0.f, s2 = 0.f;
    #pragma unroll
    for (int q = 0; q < 4; ++q) {
        const int nn = q*64 + l;
        const float* p = p2 + ((size_t)nn*16 + g)*6 + 2*kind;
        s += p[0]; s2 += p[1];
    }
    #pragma unroll
    for (int off = 32; off; off >>= 1) { s += __shfl_down(s, off); s2 += __shfl_down(s2, off); }
    if (l == 0) {
        const float mean = s * (1.f/1048576.f);
        const float var  = s2 * (1.f/1048576.f) - mean*mean;
        a2[ch] = gamma2[ch] * rsqrtf(var + 1e-5f);
    }
}

// ---------------- Kernel 6: bn3 stats (bf16 attn) -> a3,b3 ----------------
__global__ __launch_bounds__(256) void k_bn3(const unsigned short* __restrict__ attnb,
                                             const unsigned short* __restrict__ attneb,
                                             const float* __restrict__ gamma,
                                             const float* __restrict__ beta,
                                             float* __restrict__ a3, float* __restrict__ b3)
{
    const int o = blockIdx.x;
    const int g = o >> 5, rem = o & 31, c = rem >> 1, sflag = rem & 1;
    const unsigned short* src = (sflag ? attneb : attnb) + (size_t)g*1024 + (size_t)c*64;
    const int tid = threadIdx.x;
    float s = 0.f, s2 = 0.f;
    for (int t = tid; t < 2048; t += 256) {
        const int n = t >> 3, i8 = (t & 7) * 8;
        const s16x8 v8 = *(const s16x8*)&src[(size_t)n*16384 + i8];
        #pragma unroll
        for (int j = 0; j < 8; ++j) {
            const float f = bf2f((unsigned short)v8[j]);
            s += f; s2 += f*f;
        }
    }
    __shared__ float rs[4], rs2[4];
    #pragma unroll
    for (int off = 32; off; off >>= 1) { s += __shfl_down(s, off); s2 += __shfl_down(s2, off); }
    if ((tid & 63) == 0) { rs[tid>>6] = s; rs2[tid>>6] = s2; }
    __syncthreads();
    if (tid == 0) {
        const float S  = rs[0]+rs[1]+rs[2]+rs[3];
        const float S2 = rs2[0]+rs2[1]+rs2[2]+rs2[3];
        const float mean = S * (1.f/16384.f);
        const float var  = S2 * (1.f/16384.f) - mean*mean;
        const float A = gamma[o] * rsqrtf(var + 1e-5f);
        a3[o] = A;
        b3[o] = beta[o] - mean*A;
    }
}

// ---------------- Kernel 7: apply bn3, sum channel pairs, transpose ----------------
__global__ __launch_bounds__(256) void k_out(const unsigned short* __restrict__ attnb,
                                             const unsigned short* __restrict__ attneb,
                                             const float* __restrict__ a3,
                                             const float* __restrict__ b3,
                                             float* __restrict__ out)
{
    const int idx = blockIdx.x*256 + threadIdx.x;
    const int i  = idx & 63;
    const int h  = (idx >> 6) & 63;
    const int oc = (idx >> 12) & 255;
    const int b  = idx >> 20;
    const int g = oc >> 4, c = oc & 15;
    const int n = b*64 + h;
    const size_t src = ((size_t)n*16 + g)*1024 + (size_t)c*64 + i;
    const int o0 = g*32 + 2*c;
    out[idx] = a3[o0]*bf2f(attnb[src]) + a3[o0+1]*bf2f(attneb[src]) + (b3[o0] + b3[o0+1]);
}

extern "C" void kernel_launch(void* const* d_in, const int* in_sizes, int n_in,
                              void* d_out, int out_size, void* d_ws, size_t ws_size,
                              hipStream_t stream) {
    const float* x    = (const float*)d_in[0];
    const float* w    = (const float*)d_in[1];
    const float* g1   = (const float*)d_in[2];
    const float* be1  = (const float*)d_in[3];
    const float* remb = (const float*)d_in[4];
    const float* g2   = (const float*)d_in[5];
    const float* g3   = (const float*)d_in[7];
    const float* be3  = (const float*)d_in[8];
    float* out = (float*)d_out;
    float* ws  = (float*)d_ws;

    unsigned short* qkvb  = (unsigned short*)(ws + OFF_QKV);
    float* a1    = ws + OFF_A1;
    float* b1    = ws + OFF_B1;
    float* p2    = ws + OFF_P2;
    float* a2    = ws + OFF_A2;
    unsigned short* attnb  = (unsigned short*)(ws + OFF_ATTN);
    unsigned short* attneb = (unsigned short*)(ws + OFF_ATTNE);
    float* a3    = ws + OFF_A3;
    float* b3    = ws + OFF_B3;
    unsigned short* imgQK = (unsigned short*)(ws + OFF_IMGQ);
    unsigned short* imgV  = (unsigned short*)(ws + OFF_IMGV);
    u64* zqk = (u64*)(ws + OFF_ZQK);
    u64* zqe = (u64*)(ws + OFF_ZQE);
    u64* zke = (u64*)(ws + OFF_ZKE);
    unsigned short* xTh = (unsigned short*)(ws + OFF_XTH);
    unsigned short* wh  = (unsigned short*)(ws + OFF_WH);
    unsigned short* wl  = (unsigned short*)(ws + OFF_WL);

    const int SHM_A = 26720;
    const int SHM_B = 33280;
    k_split<<<256, 256, 0, stream>>>(x, xTh);
    k_wsplit<<<129, 256, 0, stream>>>(w, remb, wh, wl, imgQK, imgV);
    k_qkv_mfma<<<dim3(4, 128), 512, 0, stream>>>(wh, wl, xTh, qkvb);
    k_bn1<<<512, 256, 0, stream>>>(qkvb, g1, be1, a1, b1);
    k_pass2<0><<<4096, 256, SHM_A, stream>>>(qkvb, a1, b1, imgQK, imgV, p2, nullptr, zqk, zqe, zke, nullptr, nullptr);
    k_bn2<<<12, 256, 0, stream>>>(p2, g2, a2);
    k_pass2<1><<<4096, 256, SHM_B, stream>>>(qkvb, a1, b1, imgQK, imgV, nullptr, a2, zqk, zqe, zke, attnb, attneb);
    k_bn3<<<512, 256, 0, stream>>>(attnb, attneb, g3, be3, a3, b3);
    k_out<<<16384, 256, 0, stream>>>(attnb, attneb, a3, b3, out);
}